// Round 1
// baseline (385.740 us; speedup 1.0000x reference)
//
#include <hip/hip_runtime.h>
#include <hip/hip_bf16.h>
#include <math.h>

#define SLEN 4096
#define CIN 256
#define C3 768
#define NH 4
#define HD 64
#define BATCH 4

typedef __attribute__((ext_vector_type(8))) short bf16x8;
typedef __attribute__((ext_vector_type(4))) float f32x4;

__device__ __forceinline__ short f2bf(float f) {
    union { float f; unsigned u; } v; v.f = f;
    unsigned r = v.u + 0x7fff + ((v.u >> 16) & 1);
    return (short)(r >> 16);
}

// ---------------- kernel W: convert weights to bf16 ----------------
__global__ void k_convert_w(const float* __restrict__ qkvw, const float* __restrict__ projw,
                            short* __restrict__ qkvw_bf, short* __restrict__ projw_bf) {
    int i = blockIdx.x * 256 + threadIdx.x;
    if (i < C3 * CIN) qkvw_bf[i] = f2bf(qkvw[i]);
    if (i < CIN * CIN) projw_bf[i] = f2bf(projw[i]);
}

// ---------------- kernel T: x [b][c][s] f32 -> xT [b][s][c] bf16 ----------------
__global__ void k_transpose_x(const float* __restrict__ x, short* __restrict__ xT) {
    __shared__ float t[32][33];
    int b = blockIdx.z;
    int c0 = blockIdx.y * 32, s0 = blockIdx.x * 32;
    int tid = threadIdx.x;
    int r = tid >> 3, c4 = (tid & 7) * 4;
    const float* src = x + ((size_t)b * CIN + c0 + r) * SLEN + s0 + c4;
    float4 v = *reinterpret_cast<const float4*>(src);
    t[r][c4 + 0] = v.x; t[r][c4 + 1] = v.y; t[r][c4 + 2] = v.z; t[r][c4 + 3] = v.w;
    __syncthreads();
    int s_r = tid >> 3, cc = (tid & 7) * 4;
    short4 o = make_short4(f2bf(t[cc + 0][s_r]), f2bf(t[cc + 1][s_r]),
                           f2bf(t[cc + 2][s_r]), f2bf(t[cc + 3][s_r]));
    *reinterpret_cast<short4*>(xT + ((size_t)b * SLEN + s0 + s_r) * CIN + c0 + cc) = o;
}

// ---------------- kernel A: QKV GEMM + BN + SiLU -> Q, K, Vt (bf16) ----------------
// Q,K: [bh][s][d]; Vt: [bh][d][s]. Q pre-scaled by hd^-0.5 * log2(e).
__launch_bounds__(256)
__global__ void k_qkv(const short* __restrict__ xT, const short* __restrict__ wbf,
                      const float* __restrict__ g, const float* __restrict__ be,
                      const float* __restrict__ mu, const float* __restrict__ va,
                      short* __restrict__ Q, short* __restrict__ Kb, short* __restrict__ Vt) {
    int wv = threadIdx.x >> 6, l = threadIdx.x & 63, lr = l & 15, lg = l >> 4;
    int b = blockIdx.z;
    int s0 = blockIdx.x * 128 + wv * 32;
    int o0 = blockIdx.y * 64;
    f32x4 acc[2][4] = {};
    const short* aptr = xT + ((size_t)b * SLEN + s0 + lr) * CIN + lg * 8;
    const short* bptr = wbf + (size_t)(o0 + lr) * CIN + lg * 8;
#pragma unroll
    for (int k0 = 0; k0 < CIN; k0 += 32) {
        bf16x8 a0 = *(const bf16x8*)(aptr + k0);
        bf16x8 a1 = *(const bf16x8*)(aptr + 16 * CIN + k0);
#pragma unroll
        for (int oj = 0; oj < 4; oj++) {
            bf16x8 bb = *(const bf16x8*)(bptr + oj * 16 * CIN + k0);
            acc[0][oj] = __builtin_amdgcn_mfma_f32_16x16x32_bf16(a0, bb, acc[0][oj], 0, 0, 0);
            acc[1][oj] = __builtin_amdgcn_mfma_f32_16x16x32_bf16(a1, bb, acc[1][oj], 0, 0, 0);
        }
    }
    int which = o0 >> 8;          // uniform per block
    int h = (o0 & 255) >> 6;      // uniform per block
    int bh = b * NH + h;
    const float QSC = 0.125f * 1.44269504088896f;
#pragma unroll
    for (int oj = 0; oj < 4; oj++) {
        int o = o0 + oj * 16 + lr;
        float sc = g[o] * rsqrtf(va[o] + 1e-5f);
        float sh = be[o] - mu[o] * sc;
        int d = o & 63;
#pragma unroll
        for (int qi = 0; qi < 2; qi++) {
#pragma unroll
            for (int i = 0; i < 4; i++) {
                float y = acc[qi][oj][i] * sc + sh;
                float z = y / (1.f + __expf(-y));
                int s = s0 + qi * 16 + lg * 4 + i;
                if (which == 0) {
                    Q[((size_t)bh * SLEN + s) * HD + d] = f2bf(z * QSC);
                } else if (which == 1) {
                    Kb[((size_t)bh * SLEN + s) * HD + d] = f2bf(z);
                } else {
                    Vt[((size_t)bh * HD + d) * SLEN + s] = f2bf(z);
                }
            }
        }
    }
}

// ---------------- kernel ATTN: flash attention ----------------
__launch_bounds__(256)
__global__ void k_attn(const short* __restrict__ Q, const short* __restrict__ Kg,
                       const short* __restrict__ Vg, short* __restrict__ aout) {
    __shared__ __align__(16) short klds[64][72];
    __shared__ __align__(16) short vlds[64][72];
    __shared__ __align__(16) short plds[4][32][72];
    int tid = threadIdx.x;
    int wv = tid >> 6, l = tid & 63, lr = l & 15, lg = l >> 4;
    int bh = blockIdx.y;
    int q0 = blockIdx.x * 128 + wv * 32;

    const short* qbase = Q + ((size_t)bh * SLEN + q0 + lr) * HD + lg * 8;
    bf16x8 qf[2][2];
    qf[0][0] = *(const bf16x8*)(qbase);
    qf[0][1] = *(const bf16x8*)(qbase + 32);
    qf[1][0] = *(const bf16x8*)(qbase + 16 * HD);
    qf[1][1] = *(const bf16x8*)(qbase + 16 * HD + 32);

    f32x4 o[2][4] = {};
    float m[2][4], ls[2][4];
#pragma unroll
    for (int qi = 0; qi < 2; qi++)
#pragma unroll
        for (int i = 0; i < 4; i++) { m[qi][i] = -1e30f; ls[qi][i] = 0.f; }

    int row = tid >> 3;
    int cseg = (tid & 7) * 8;
    const short* kg = Kg + (size_t)bh * SLEN * HD;
    const short* vg = Vg + (size_t)bh * HD * SLEN;

    for (int t = 0; t < SLEN / 64; ++t) {
        __syncthreads();
#pragma unroll
        for (int rr = 0; rr < 2; ++rr) {
            int r2 = row + rr * 32;
            *(int4*)(&klds[r2][cseg]) = *(const int4*)(kg + (size_t)(t * 64 + r2) * HD + cseg);
            *(int4*)(&vlds[r2][cseg]) = *(const int4*)(vg + (size_t)r2 * SLEN + t * 64 + cseg);
        }
        __syncthreads();

        // QK^T
        f32x4 sv[2][4] = {};
#pragma unroll
        for (int ks = 0; ks < 2; ++ks) {
            bf16x8 kb[4];
#pragma unroll
            for (int kj = 0; kj < 4; kj++) kb[kj] = *(const bf16x8*)(&klds[kj * 16 + lr][ks * 32 + lg * 8]);
#pragma unroll
            for (int qi = 0; qi < 2; qi++)
#pragma unroll
                for (int kj = 0; kj < 4; kj++)
                    sv[qi][kj] = __builtin_amdgcn_mfma_f32_16x16x32_bf16(qf[qi][ks], kb[kj], sv[qi][kj], 0, 0, 0);
        }

        // online softmax (logits already in log2 domain via Q pre-scale)
        float p[2][4][4];
#pragma unroll
        for (int qi = 0; qi < 2; qi++) {
#pragma unroll
            for (int i = 0; i < 4; i++) {
                float mx = fmaxf(fmaxf(sv[qi][0][i], sv[qi][1][i]), fmaxf(sv[qi][2][i], sv[qi][3][i]));
#pragma unroll
                for (int sh = 1; sh < 16; sh <<= 1) mx = fmaxf(mx, __shfl_xor(mx, sh));
                float mn = fmaxf(m[qi][i], mx);
                float al = exp2f(m[qi][i] - mn);
                float rs = 0.f;
#pragma unroll
                for (int kj = 0; kj < 4; kj++) {
                    float pv = exp2f(sv[qi][kj][i] - mn);
                    p[qi][kj][i] = pv; rs += pv;
                }
#pragma unroll
                for (int sh = 1; sh < 16; sh <<= 1) rs += __shfl_xor(rs, sh);
                ls[qi][i] = ls[qi][i] * al + rs;
                m[qi][i] = mn;
#pragma unroll
                for (int dj = 0; dj < 4; dj++) o[qi][dj][i] *= al;
            }
        }

        // P -> per-wave LDS (bf16)
#pragma unroll
        for (int qi = 0; qi < 2; qi++)
#pragma unroll
            for (int kj = 0; kj < 4; kj++)
#pragma unroll
                for (int i = 0; i < 4; i++)
                    plds[wv][qi * 16 + lg * 4 + i][kj * 16 + lr] = f2bf(p[qi][kj][i]);
        asm volatile("s_waitcnt lgkmcnt(0)" ::: "memory");

        // PV
#pragma unroll
        for (int ks = 0; ks < 2; ks++) {
            bf16x8 pa[2], vb[4];
            pa[0] = *(const bf16x8*)(&plds[wv][lr][ks * 32 + lg * 8]);
            pa[1] = *(const bf16x8*)(&plds[wv][16 + lr][ks * 32 + lg * 8]);
#pragma unroll
            for (int dj = 0; dj < 4; dj++) vb[dj] = *(const bf16x8*)(&vlds[dj * 16 + lr][ks * 32 + lg * 8]);
#pragma unroll
            for (int qi = 0; qi < 2; qi++)
#pragma unroll
                for (int dj = 0; dj < 4; dj++)
                    o[qi][dj] = __builtin_amdgcn_mfma_f32_16x16x32_bf16(pa[qi], vb[dj], o[qi][dj], 0, 0, 0);
        }
    }

    // epilogue: normalize, transpose via plds, store [b][s][c] bf16
#pragma unroll
    for (int qi = 0; qi < 2; qi++)
#pragma unroll
        for (int i = 0; i < 4; i++) {
            float inv = 1.f / ls[qi][i];
#pragma unroll
            for (int dj = 0; dj < 4; dj++)
                plds[wv][qi * 16 + lg * 4 + i][dj * 16 + lr] = f2bf(o[qi][dj][i] * inv);
        }
    asm volatile("s_waitcnt lgkmcnt(0)" ::: "memory");
    int b = bh >> 2, h = bh & 3;
    int r2 = l >> 1;
    int c0 = (l & 1) * 32;
    short* ob = aout + ((size_t)b * SLEN + q0 + r2) * CIN + h * HD + c0;
#pragma unroll
    for (int j = 0; j < 4; j++) {
        *(int4*)(ob + j * 8) = *(const int4*)(&plds[wv][r2][c0 + j * 8]);
    }
}

// ---------------- kernel C: proj GEMM + BN + SiLU -> fp32 out ----------------
__launch_bounds__(256)
__global__ void k_proj(const short* __restrict__ aout, const short* __restrict__ wbf,
                       const float* __restrict__ g, const float* __restrict__ be,
                       const float* __restrict__ mu, const float* __restrict__ va,
                       float* __restrict__ out) {
    int wv = threadIdx.x >> 6, l = threadIdx.x & 63, lr = l & 15, lg = l >> 4;
    int b = blockIdx.z;
    int s0 = blockIdx.x * 128 + wv * 32;
    int o0 = blockIdx.y * 64;
    f32x4 acc[2][4] = {};
    const short* aptr = aout + ((size_t)b * SLEN + s0 + lr) * CIN + lg * 8;
    const short* bptr = wbf + (size_t)(o0 + lr) * CIN + lg * 8;
#pragma unroll
    for (int k0 = 0; k0 < CIN; k0 += 32) {
        bf16x8 a0 = *(const bf16x8*)(aptr + k0);
        bf16x8 a1 = *(const bf16x8*)(aptr + 16 * CIN + k0);
#pragma unroll
        for (int oj = 0; oj < 4; oj++) {
            bf16x8 bb = *(const bf16x8*)(bptr + oj * 16 * CIN + k0);
            acc[0][oj] = __builtin_amdgcn_mfma_f32_16x16x32_bf16(a0, bb, acc[0][oj], 0, 0, 0);
            acc[1][oj] = __builtin_amdgcn_mfma_f32_16x16x32_bf16(a1, bb, acc[1][oj], 0, 0, 0);
        }
    }
#pragma unroll
    for (int oj = 0; oj < 4; oj++) {
        int o = o0 + oj * 16 + lr;
        float sc = g[o] * rsqrtf(va[o] + 1e-5f);
        float sh = be[o] - mu[o] * sc;
#pragma unroll
        for (int qi = 0; qi < 2; qi++) {
            float4 st;
            float* stp = &st.x;
#pragma unroll
            for (int i = 0; i < 4; i++) {
                float y = acc[qi][oj][i] * sc + sh;
                stp[i] = y / (1.f + __expf(-y));
            }
            int s = s0 + qi * 16 + lg * 4;
            *reinterpret_cast<float4*>(out + ((size_t)b * CIN + o) * SLEN + s) = st;
        }
    }
}

extern "C" void kernel_launch(void* const* d_in, const int* in_sizes, int n_in,
                              void* d_out, int out_size, void* d_ws, size_t ws_size,
                              hipStream_t stream) {
    const float* x    = (const float*)d_in[0];
    const float* qkvw = (const float*)d_in[1];
    const float* qg   = (const float*)d_in[2];
    const float* qbe  = (const float*)d_in[3];
    const float* qmu  = (const float*)d_in[4];
    const float* qva  = (const float*)d_in[5];
    const float* pw   = (const float*)d_in[6];
    const float* pg   = (const float*)d_in[7];
    const float* pbe  = (const float*)d_in[8];
    const float* pmu  = (const float*)d_in[9];
    const float* pva  = (const float*)d_in[10];
    float* out = (float*)d_out;

    char* ws = (char*)d_ws;
    short* xT       = (short*)(ws);                 // 8,388,608 B
    short* qkvw_bf  = (short*)(ws + 8388608);       //   393,216 B
    short* projw_bf = (short*)(ws + 8781824);       //   131,072 B
    short* Qb       = (short*)(ws + 8912896);       // 8,388,608 B
    short* Kb       = (short*)(ws + 17301504);      // 8,388,608 B
    short* Vt       = (short*)(ws + 25690112);      // 8,388,608 B
    short* aout     = (short*)(ws + 34078720);      // 8,388,608 B

    k_convert_w<<<768, 256, 0, stream>>>(qkvw, pw, qkvw_bf, projw_bf);
    k_transpose_x<<<dim3(128, 8, 4), 256, 0, stream>>>(x, xT);
    k_qkv<<<dim3(32, 12, 4), 256, 0, stream>>>(xT, qkvw_bf, qg, qbe, qmu, qva, Qb, Kb, Vt);
    k_attn<<<dim3(32, 16), 256, 0, stream>>>(Qb, Kb, Vt, aout);
    k_proj<<<dim3(32, 4, 4), 256, 0, stream>>>(aout, projw_bf, pg, pbe, pmu, pva, out);
}

// Round 2
// 221.245 us; speedup vs baseline: 1.7435x; 1.7435x over previous
//
#include <hip/hip_runtime.h>
#include <hip/hip_bf16.h>
#include <math.h>

#define SLEN 4096
#define CIN 256
#define C3 768
#define NH 4
#define HD 64
#define BATCH 4

typedef __attribute__((ext_vector_type(8))) short bf16x8;
typedef __attribute__((ext_vector_type(4))) float f32x4;
typedef __attribute__((ext_vector_type(16))) float f32x16;

__device__ __forceinline__ short f2bf(float f) {
    union { float f; unsigned u; } v; v.f = f;
    unsigned r = v.u + 0x7fff + ((v.u >> 16) & 1);
    return (short)(r >> 16);
}

__device__ __forceinline__ unsigned pack2(float a, float b) {
    float2 t; t.x = a; t.y = b;
    __hip_bfloat162 h = __float22bfloat162_rn(t);
    union { __hip_bfloat162 h; unsigned u; } c; c.h = h;
    return c.u;
}

// ---------------- kernel W: convert weights to bf16 ----------------
__global__ void k_convert_w(const float* __restrict__ qkvw, const float* __restrict__ projw,
                            short* __restrict__ qkvw_bf, short* __restrict__ projw_bf) {
    int i = blockIdx.x * 256 + threadIdx.x;
    if (i < C3 * CIN) qkvw_bf[i] = f2bf(qkvw[i]);
    if (i < CIN * CIN) projw_bf[i] = f2bf(projw[i]);
}

// ---------------- kernel T: x [b][c][s] f32 -> xT [b][s][c] bf16 ----------------
__global__ void k_transpose_x(const float* __restrict__ x, short* __restrict__ xT) {
    __shared__ float t[32][33];
    int b = blockIdx.z;
    int c0 = blockIdx.y * 32, s0 = blockIdx.x * 32;
    int tid = threadIdx.x;
    int r = tid >> 3, c4 = (tid & 7) * 4;
    const float* src = x + ((size_t)b * CIN + c0 + r) * SLEN + s0 + c4;
    float4 v = *reinterpret_cast<const float4*>(src);
    t[r][c4 + 0] = v.x; t[r][c4 + 1] = v.y; t[r][c4 + 2] = v.z; t[r][c4 + 3] = v.w;
    __syncthreads();
    int s_r = tid >> 3, cc = (tid & 7) * 4;
    short4 o = make_short4(f2bf(t[cc + 0][s_r]), f2bf(t[cc + 1][s_r]),
                           f2bf(t[cc + 2][s_r]), f2bf(t[cc + 3][s_r]));
    *reinterpret_cast<short4*>(xT + ((size_t)b * SLEN + s0 + s_r) * CIN + c0 + cc) = o;
}

// ---------------- kernel A: QKV GEMM + BN + SiLU -> Q, K, Vt (bf16) ----------------
// Q,K: [bh][s][d]; Vt: [bh][d][s]. Q pre-scaled by hd^-0.5 * log2(e).
__launch_bounds__(256)
__global__ void k_qkv(const short* __restrict__ xT, const short* __restrict__ wbf,
                      const float* __restrict__ g, const float* __restrict__ be,
                      const float* __restrict__ mu, const float* __restrict__ va,
                      short* __restrict__ Q, short* __restrict__ Kb, short* __restrict__ Vt) {
    int wv = threadIdx.x >> 6, l = threadIdx.x & 63, lr = l & 15, lg = l >> 4;
    int b = blockIdx.z;
    int s0 = blockIdx.x * 128 + wv * 32;
    int o0 = blockIdx.y * 64;
    f32x4 acc[2][4] = {};
    const short* aptr = xT + ((size_t)b * SLEN + s0 + lr) * CIN + lg * 8;
    const short* bptr = wbf + (size_t)(o0 + lr) * CIN + lg * 8;
#pragma unroll
    for (int k0 = 0; k0 < CIN; k0 += 32) {
        bf16x8 a0 = *(const bf16x8*)(aptr + k0);
        bf16x8 a1 = *(const bf16x8*)(aptr + 16 * CIN + k0);
#pragma unroll
        for (int oj = 0; oj < 4; oj++) {
            bf16x8 bb = *(const bf16x8*)(bptr + oj * 16 * CIN + k0);
            acc[0][oj] = __builtin_amdgcn_mfma_f32_16x16x32_bf16(a0, bb, acc[0][oj], 0, 0, 0);
            acc[1][oj] = __builtin_amdgcn_mfma_f32_16x16x32_bf16(a1, bb, acc[1][oj], 0, 0, 0);
        }
    }
    int which = o0 >> 8;          // uniform per block
    int h = (o0 & 255) >> 6;      // uniform per block
    int bh = b * NH + h;
    const float QSC = 0.125f * 1.44269504088896f;
#pragma unroll
    for (int oj = 0; oj < 4; oj++) {
        int o = o0 + oj * 16 + lr;
        float sc = g[o] * rsqrtf(va[o] + 1e-5f);
        float sh = be[o] - mu[o] * sc;
        int d = o & 63;
#pragma unroll
        for (int qi = 0; qi < 2; qi++) {
#pragma unroll
            for (int i = 0; i < 4; i++) {
                float y = acc[qi][oj][i] * sc + sh;
                float z = y / (1.f + __expf(-y));
                int s = s0 + qi * 16 + lg * 4 + i;
                if (which == 0) {
                    Q[((size_t)bh * SLEN + s) * HD + d] = f2bf(z * QSC);
                } else if (which == 1) {
                    Kb[((size_t)bh * SLEN + s) * HD + d] = f2bf(z);
                } else {
                    Vt[((size_t)bh * HD + d) * SLEN + s] = f2bf(z);
                }
            }
        }
    }
}

// ---------------- kernel ATTN: flash attention, swapped-QK^T in-register softmax ----
// 4 waves/block, 32 q-rows/wave, KVBLK=64, double-buffered K/Vt in LDS (XOR-swizzled).
// S^T = mfma_32x32x16(K, Q): lane holds 32 P values for q = lane&31 (k split by hi=lane>>5).
__launch_bounds__(256)
__global__ void k_attn(const short* __restrict__ Q, const short* __restrict__ Kg,
                       const short* __restrict__ Vg, short* __restrict__ aout) {
    __shared__ __align__(16) short klds[2][64][64];
    __shared__ __align__(16) short vlds[2][64][64];
    int tid = threadIdx.x;
    int wv = tid >> 6, l = tid & 63;
    int q32 = l & 31;           // q within wave tile (and k-row / d-row for A-frags)
    int hi  = l >> 5;
    int bh = blockIdx.y;
    int q0 = blockIdx.x * 128 + wv * 32;

    const short* kg = Kg + (size_t)bh * SLEN * HD;
    const short* vg = Vg + (size_t)bh * HD * SLEN;

    // Q B-fragments: rows q=lane&31, frag jd holds d = jd*16 + hi*8 + 0..7
    bf16x8 qf[4];
    {
        const short* qb = Q + ((size_t)bh * SLEN + q0 + q32) * HD + hi * 8;
        qf[0] = *(const bf16x8*)(qb);
        qf[1] = *(const bf16x8*)(qb + 16);
        qf[2] = *(const bf16x8*)(qb + 32);
        qf[3] = *(const bf16x8*)(qb + 48);
    }

    f32x16 oacc0 = {}, oacc1 = {};
    float mrun = -1e30f, lrun = 0.f;

    // staging geometry: wave wv stages rows wv*16..wv*16+15 (two 8-row groups)
    int srow = wv * 16 + (l >> 3);
    int gs = l & 7;
    int swcol = (gs ^ (l >> 3)) * 8;   // swizzled col (shorts), row&7 == l>>3
    int4 rK0, rK1, rV0, rV1;

#define LOADREG(t) do { \
    const short* kgt = kg + ((size_t)(t) * 64 + srow) * HD + gs * 8; \
    rK0 = *(const int4*)(kgt); \
    rK1 = *(const int4*)(kgt + 8 * HD); \
    const short* vgt = vg + (size_t)srow * SLEN + (t) * 64 + gs * 8; \
    rV0 = *(const int4*)(vgt); \
    rV1 = *(const int4*)(vgt + 8 * SLEN); \
} while (0)

#define WRITELDS(bufb) do { \
    *(int4*)(&klds[bufb][srow][swcol]) = rK0; \
    *(int4*)(&klds[bufb][srow + 8][swcol]) = rK1; \
    *(int4*)(&vlds[bufb][srow][swcol]) = rV0; \
    *(int4*)(&vlds[bufb][srow + 8][swcol]) = rV1; \
} while (0)

#define BAR() do { asm volatile("" ::: "memory"); __builtin_amdgcn_s_barrier(); asm volatile("" ::: "memory"); } while (0)

    LOADREG(0);
    WRITELDS(0);
    LOADREG(1);
    asm volatile("s_waitcnt lgkmcnt(0)" ::: "memory");
    BAR();

    const int swz = (l & 7) << 4;  // byte-XOR swizzle term

    for (int t = 0; t < SLEN / 64; ++t) {
        if (t < SLEN / 64 - 1) {
            WRITELDS((t + 1) & 1);             // stage tile t+1 into idle buffer
            if (t + 2 < SLEN / 64) LOADREG(t + 2);
        }

        const short* kb = &klds[t & 1][0][0];
        const short* vb = &vlds[t & 1][0][0];
        const short* krow0 = kb + q32 * 64;
        const short* krow1 = kb + (32 + q32) * 64;

        // ---- QK^T: S^T[k][q], two 32-k chunks ----
        f32x16 s0v = {}, s1v = {};
#pragma unroll
        for (int jd = 0; jd < 4; ++jd) {
            int col = ((jd * 32 + hi * 16) ^ swz) >> 1;
            bf16x8 k0 = *(const bf16x8*)(krow0 + col);
            bf16x8 k1 = *(const bf16x8*)(krow1 + col);
            s0v = __builtin_amdgcn_mfma_f32_32x32x16_bf16(k0, qf[jd], s0v, 0, 0, 0);
            s1v = __builtin_amdgcn_mfma_f32_32x32x16_bf16(k1, qf[jd], s1v, 0, 0, 0);
        }

        // ---- online softmax, fully in-register (log2 domain) ----
        float pm = -1e30f;
#pragma unroll
        for (int r = 0; r < 16; ++r) { pm = fmaxf(pm, s0v[r]); pm = fmaxf(pm, s1v[r]); }
        pm = fmaxf(pm, __shfl_xor(pm, 32));
        float mn = fmaxf(mrun, pm);
        float al = exp2f(mrun - mn);
        mrun = mn;
        float rs = 0.f;
#pragma unroll
        for (int r = 0; r < 16; ++r) {
            float e0 = exp2f(s0v[r] - mn); s0v[r] = e0; rs += e0;
            float e1 = exp2f(s1v[r] - mn); s1v[r] = e1; rs += e1;
        }
        rs += __shfl_xor(rs, 32);
        lrun = lrun * al + rs;
#pragma unroll
        for (int r = 0; r < 16; ++r) { oacc0[r] *= al; oacc1[r] *= al; }

        // ---- pack P to bf16 pairs: pk[c][m][w], reg r=4m+e holds k=c*32+e+8m+4hi ----
        unsigned pk[2][4][2];
#pragma unroll
        for (int m4 = 0; m4 < 4; ++m4) {
            pk[0][m4][0] = pack2(s0v[4 * m4 + 0], s0v[4 * m4 + 1]);
            pk[0][m4][1] = pack2(s0v[4 * m4 + 2], s0v[4 * m4 + 3]);
            pk[1][m4][0] = pack2(s1v[4 * m4 + 0], s1v[4 * m4 + 1]);
            pk[1][m4][1] = pack2(s1v[4 * m4 + 2], s1v[4 * m4 + 3]);
        }

        // ---- PV: O^T[d][q] += Vt·P^T, P B-frag assembled via shfl_xor(32) ----
        const short* vrow0 = vb + q32 * 64;
        const short* vrow1 = vb + (32 + q32) * 64;
#pragma unroll
        for (int kc = 0; kc < 4; ++kc) {
            const int c = kc >> 1, mlo = 2 * (kc & 1);
            unsigned own0 = hi ? pk[c][mlo + 1][0] : pk[c][mlo][0];
            unsigned own1 = hi ? pk[c][mlo + 1][1] : pk[c][mlo][1];
            unsigned snd0 = hi ? pk[c][mlo][0] : pk[c][mlo + 1][0];
            unsigned snd1 = hi ? pk[c][mlo][1] : pk[c][mlo + 1][1];
            unsigned rcv0 = (unsigned)__shfl_xor((int)snd0, 32);
            unsigned rcv1 = (unsigned)__shfl_xor((int)snd1, 32);
            union { bf16x8 v; unsigned u[4]; } pf;
            pf.u[0] = hi ? rcv0 : own0;
            pf.u[1] = hi ? rcv1 : own1;
            pf.u[2] = hi ? own0 : rcv0;
            pf.u[3] = hi ? own1 : rcv1;
            int col = ((kc * 32 + hi * 16) ^ swz) >> 1;
            bf16x8 v0 = *(const bf16x8*)(vrow0 + col);
            bf16x8 v1 = *(const bf16x8*)(vrow1 + col);
            oacc0 = __builtin_amdgcn_mfma_f32_32x32x16_bf16(v0, pf.v, oacc0, 0, 0, 0);
            oacc1 = __builtin_amdgcn_mfma_f32_32x32x16_bf16(v1, pf.v, oacc1, 0, 0, 0);
        }

        if (t < SLEN / 64 - 1) {
            asm volatile("s_waitcnt lgkmcnt(0)" ::: "memory");
            BAR();
        }
    }

    // ---- epilogue: O^T/l -> aout [b][s][c] bf16 ----
    float inv = 1.f / lrun;
    int b = bh >> 2, h = bh & 3;
    short* ob = aout + ((size_t)b * SLEN + q0 + q32) * CIN + h * HD;
#pragma unroll
    for (int g4 = 0; g4 < 4; ++g4) {
        uint2 st0, st1;
        st0.x = pack2(oacc0[4 * g4 + 0] * inv, oacc0[4 * g4 + 1] * inv);
        st0.y = pack2(oacc0[4 * g4 + 2] * inv, oacc0[4 * g4 + 3] * inv);
        st1.x = pack2(oacc1[4 * g4 + 0] * inv, oacc1[4 * g4 + 1] * inv);
        st1.y = pack2(oacc1[4 * g4 + 2] * inv, oacc1[4 * g4 + 3] * inv);
        *(uint2*)(ob + 8 * g4 + 4 * hi) = st0;
        *(uint2*)(ob + 32 + 8 * g4 + 4 * hi) = st1;
    }
#undef LOADREG
#undef WRITELDS
#undef BAR
}

// ---------------- kernel C: proj GEMM + BN + SiLU -> fp32 out ----------------
__launch_bounds__(256)
__global__ void k_proj(const short* __restrict__ aout, const short* __restrict__ wbf,
                       const float* __restrict__ g, const float* __restrict__ be,
                       const float* __restrict__ mu, const float* __restrict__ va,
                       float* __restrict__ out) {
    int wv = threadIdx.x >> 6, l = threadIdx.x & 63, lr = l & 15, lg = l >> 4;
    int b = blockIdx.z;
    int s0 = blockIdx.x * 128 + wv * 32;
    int o0 = blockIdx.y * 64;
    f32x4 acc[2][4] = {};
    const short* aptr = aout + ((size_t)b * SLEN + s0 + lr) * CIN + lg * 8;
    const short* bptr = wbf + (size_t)(o0 + lr) * CIN + lg * 8;
#pragma unroll
    for (int k0 = 0; k0 < CIN; k0 += 32) {
        bf16x8 a0 = *(const bf16x8*)(aptr + k0);
        bf16x8 a1 = *(const bf16x8*)(aptr + 16 * CIN + k0);
#pragma unroll
        for (int oj = 0; oj < 4; oj++) {
            bf16x8 bb = *(const bf16x8*)(bptr + oj * 16 * CIN + k0);
            acc[0][oj] = __builtin_amdgcn_mfma_f32_16x16x32_bf16(a0, bb, acc[0][oj], 0, 0, 0);
            acc[1][oj] = __builtin_amdgcn_mfma_f32_16x16x32_bf16(a1, bb, acc[1][oj], 0, 0, 0);
        }
    }
#pragma unroll
    for (int oj = 0; oj < 4; oj++) {
        int o = o0 + oj * 16 + lr;
        float sc = g[o] * rsqrtf(va[o] + 1e-5f);
        float sh = be[o] - mu[o] * sc;
#pragma unroll
        for (int qi = 0; qi < 2; qi++) {
            float4 st;
            float* stp = &st.x;
#pragma unroll
            for (int i = 0; i < 4; i++) {
                float y = acc[qi][oj][i] * sc + sh;
                stp[i] = y / (1.f + __expf(-y));
            }
            int s = s0 + qi * 16 + lg * 4;
            *reinterpret_cast<float4*>(out + ((size_t)b * CIN + o) * SLEN + s) = st;
        }
    }
}

extern "C" void kernel_launch(void* const* d_in, const int* in_sizes, int n_in,
                              void* d_out, int out_size, void* d_ws, size_t ws_size,
                              hipStream_t stream) {
    const float* x    = (const float*)d_in[0];
    const float* qkvw = (const float*)d_in[1];
    const float* qg   = (const float*)d_in[2];
    const float* qbe  = (const float*)d_in[3];
    const float* qmu  = (const float*)d_in[4];
    const float* qva  = (const float*)d_in[5];
    const float* pw   = (const float*)d_in[6];
    const float* pg   = (const float*)d_in[7];
    const float* pbe  = (const float*)d_in[8];
    const float* pmu  = (const float*)d_in[9];
    const float* pva  = (const float*)d_in[10];
    float* out = (float*)d_out;

    char* ws = (char*)d_ws;
    short* xT       = (short*)(ws);                 // 8,388,608 B
    short* qkvw_bf  = (short*)(ws + 8388608);       //   393,216 B
    short* projw_bf = (short*)(ws + 8781824);       //   131,072 B
    short* Qb       = (short*)(ws + 8912896);       // 8,388,608 B
    short* Kb       = (short*)(ws + 17301504);      // 8,388,608 B
    short* Vt       = (short*)(ws + 25690112);      // 8,388,608 B
    short* aout     = (short*)(ws + 34078720);      // 8,388,608 B

    k_convert_w<<<768, 256, 0, stream>>>(qkvw, pw, qkvw_bf, projw_bf);
    k_transpose_x<<<dim3(128, 8, 4), 256, 0, stream>>>(x, xT);
    k_qkv<<<dim3(32, 12, 4), 256, 0, stream>>>(xT, qkvw_bf, qg, qbe, qmu, qva, Qb, Kb, Vt);
    k_attn<<<dim3(32, 16), 256, 0, stream>>>(Qb, Kb, Vt, aout);
    k_proj<<<dim3(32, 4, 4), 256, 0, stream>>>(aout, projw_bf, pg, pbe, pmu, pva, out);
}

// Round 3
// 206.266 us; speedup vs baseline: 1.8701x; 1.0726x over previous
//
#include <hip/hip_runtime.h>
#include <hip/hip_bf16.h>
#include <math.h>

#define SLEN 4096
#define CIN 256
#define C3 768
#define NH 4
#define HD 64
#define BATCH 4

typedef __attribute__((ext_vector_type(8))) short bf16x8;
typedef __attribute__((ext_vector_type(4))) float f32x4;
typedef __attribute__((ext_vector_type(16))) float f32x16;

__device__ __forceinline__ short f2bf(float f) {
    union { float f; unsigned u; } v; v.f = f;
    unsigned r = v.u + 0x7fff + ((v.u >> 16) & 1);
    return (short)(r >> 16);
}

__device__ __forceinline__ unsigned pack2(float a, float b) {
    float2 t; t.x = a; t.y = b;
    __hip_bfloat162 h = __float22bfloat162_rn(t);
    union { __hip_bfloat162 h; unsigned u; } c; c.h = h;
    return c.u;
}

// ---------------- kernel W: convert weights to bf16 ----------------
__global__ void k_convert_w(const float* __restrict__ qkvw, const float* __restrict__ projw,
                            short* __restrict__ qkvw_bf, short* __restrict__ projw_bf) {
    int i = blockIdx.x * 256 + threadIdx.x;
    if (i < C3 * CIN) qkvw_bf[i] = f2bf(qkvw[i]);
    if (i < CIN * CIN) projw_bf[i] = f2bf(projw[i]);
}

// ---------------- kernel T: x [b][c][s] f32 -> xT [b][s][c] bf16 ----------------
__global__ void k_transpose_x(const float* __restrict__ x, short* __restrict__ xT) {
    __shared__ float t[32][33];
    int b = blockIdx.z;
    int c0 = blockIdx.y * 32, s0 = blockIdx.x * 32;
    int tid = threadIdx.x;
    int r = tid >> 3, c4 = (tid & 7) * 4;
    const float* src = x + ((size_t)b * CIN + c0 + r) * SLEN + s0 + c4;
    float4 v = *reinterpret_cast<const float4*>(src);
    t[r][c4 + 0] = v.x; t[r][c4 + 1] = v.y; t[r][c4 + 2] = v.z; t[r][c4 + 3] = v.w;
    __syncthreads();
    int s_r = tid >> 3, cc = (tid & 7) * 4;
    short4 o = make_short4(f2bf(t[cc + 0][s_r]), f2bf(t[cc + 1][s_r]),
                           f2bf(t[cc + 2][s_r]), f2bf(t[cc + 3][s_r]));
    *reinterpret_cast<short4*>(xT + ((size_t)b * SLEN + s0 + s_r) * CIN + c0 + cc) = o;
}

// ---------------- kernel A: QKV GEMM + BN + SiLU -> Q, K, Vt (bf16) ----------------
// Q,K: [bh][s][d]; Vt: [bh][d][s]. Q pre-scaled by hd^-0.5 * log2(e).
__launch_bounds__(256)
__global__ void k_qkv(const short* __restrict__ xT, const short* __restrict__ wbf,
                      const float* __restrict__ g, const float* __restrict__ be,
                      const float* __restrict__ mu, const float* __restrict__ va,
                      short* __restrict__ Q, short* __restrict__ Kb, short* __restrict__ Vt) {
    int wv = threadIdx.x >> 6, l = threadIdx.x & 63, lr = l & 15, lg = l >> 4;
    int b = blockIdx.z;
    int s0 = blockIdx.x * 128 + wv * 32;
    int o0 = blockIdx.y * 64;
    f32x4 acc[2][4] = {};
    const short* aptr = xT + ((size_t)b * SLEN + s0 + lr) * CIN + lg * 8;
    const short* bptr = wbf + (size_t)(o0 + lr) * CIN + lg * 8;
#pragma unroll
    for (int k0 = 0; k0 < CIN; k0 += 32) {
        bf16x8 a0 = *(const bf16x8*)(aptr + k0);
        bf16x8 a1 = *(const bf16x8*)(aptr + 16 * CIN + k0);
#pragma unroll
        for (int oj = 0; oj < 4; oj++) {
            bf16x8 bb = *(const bf16x8*)(bptr + oj * 16 * CIN + k0);
            acc[0][oj] = __builtin_amdgcn_mfma_f32_16x16x32_bf16(a0, bb, acc[0][oj], 0, 0, 0);
            acc[1][oj] = __builtin_amdgcn_mfma_f32_16x16x32_bf16(a1, bb, acc[1][oj], 0, 0, 0);
        }
    }
    int which = o0 >> 8;          // uniform per block
    int h = (o0 & 255) >> 6;      // uniform per block
    int bh = b * NH + h;
    const float QSC = 0.125f * 1.44269504088896f;
#pragma unroll
    for (int oj = 0; oj < 4; oj++) {
        int o = o0 + oj * 16 + lr;
        float sc = g[o] * rsqrtf(va[o] + 1e-5f);
        float sh = be[o] - mu[o] * sc;
        int d = o & 63;
#pragma unroll
        for (int qi = 0; qi < 2; qi++) {
#pragma unroll
            for (int i = 0; i < 4; i++) {
                float y = acc[qi][oj][i] * sc + sh;
                float z = y / (1.f + __expf(-y));
                int s = s0 + qi * 16 + lg * 4 + i;
                if (which == 0) {
                    Q[((size_t)bh * SLEN + s) * HD + d] = f2bf(z * QSC);
                } else if (which == 1) {
                    Kb[((size_t)bh * SLEN + s) * HD + d] = f2bf(z);
                } else {
                    Vt[((size_t)bh * HD + d) * SLEN + s] = f2bf(z);
                }
            }
        }
    }
}

// ---------------- kernel ATTN: flash attention, swapped-QK^T in-register softmax ----
// 4 waves/block, 32 q-rows/wave, KVBLK=64, double-buffered K/Vt in LDS (XOR-swizzled).
// S^T = mfma_32x32x16(K, Q): lane holds 32 P values for q = lane&31 (k split by hi=lane>>5).
// Row-sum via MFMA(ones, P); P-fragment assembly via v_permlane32_swap; defer-max rescale.
__launch_bounds__(256)
__global__ void k_attn(const short* __restrict__ Q, const short* __restrict__ Kg,
                       const short* __restrict__ Vg, short* __restrict__ aout) {
    __shared__ __align__(16) short klds[2][64][64];
    __shared__ __align__(16) short vlds[2][64][64];
    int tid = threadIdx.x;
    int wv = tid >> 6, l = tid & 63;
    int q32 = l & 31;           // q within wave tile (and k-row / d-row for A-frags)
    int hi  = l >> 5;
    int bh = blockIdx.y;
    int q0 = blockIdx.x * 128 + wv * 32;

    const short* kg = Kg + (size_t)bh * SLEN * HD;
    const short* vg = Vg + (size_t)bh * HD * SLEN;

    // Q B-fragments: rows q=lane&31, frag jd holds d = jd*16 + hi*8 + 0..7
    bf16x8 qf[4];
    {
        const short* qb = Q + ((size_t)bh * SLEN + q0 + q32) * HD + hi * 8;
        qf[0] = *(const bf16x8*)(qb);
        qf[1] = *(const bf16x8*)(qb + 16);
        qf[2] = *(const bf16x8*)(qb + 32);
        qf[3] = *(const bf16x8*)(qb + 48);
    }

    // ones A-fragment for the row-sum MFMA
    bf16x8 ones;
#pragma unroll
    for (int e = 0; e < 8; ++e) ones[e] = (short)0x3F80;

    f32x16 oacc0 = {}, oacc1 = {}, sacc = {};
    float mrun = -1e30f;

    // staging geometry: wave wv stages rows wv*16..wv*16+15 (two 8-row groups)
    int srow = wv * 16 + (l >> 3);
    int gs = l & 7;
    int swcol = (gs ^ (l >> 3)) * 8;   // swizzled col (shorts), row&7 == l>>3
    int4 rK0, rK1, rV0, rV1;

#define LOADREG(t) do { \
    const short* kgt = kg + ((size_t)(t) * 64 + srow) * HD + gs * 8; \
    rK0 = *(const int4*)(kgt); \
    rK1 = *(const int4*)(kgt + 8 * HD); \
    const short* vgt = vg + (size_t)srow * SLEN + (t) * 64 + gs * 8; \
    rV0 = *(const int4*)(vgt); \
    rV1 = *(const int4*)(vgt + 8 * SLEN); \
} while (0)

#define WRITELDS(bufb) do { \
    *(int4*)(&klds[bufb][srow][swcol]) = rK0; \
    *(int4*)(&klds[bufb][srow + 8][swcol]) = rK1; \
    *(int4*)(&vlds[bufb][srow][swcol]) = rV0; \
    *(int4*)(&vlds[bufb][srow + 8][swcol]) = rV1; \
} while (0)

#define BAR() do { asm volatile("" ::: "memory"); __builtin_amdgcn_s_barrier(); asm volatile("" ::: "memory"); } while (0)

    LOADREG(0);
    WRITELDS(0);
    LOADREG(1);
    asm volatile("s_waitcnt lgkmcnt(0)" ::: "memory");
    BAR();

    const int swz = (l & 7) << 4;  // byte-XOR swizzle term

    for (int t = 0; t < SLEN / 64; ++t) {
        if (t < SLEN / 64 - 1) {
            WRITELDS((t + 1) & 1);             // stage tile t+1 into idle buffer
            if (t + 2 < SLEN / 64) LOADREG(t + 2);
        }

        const short* kb = &klds[t & 1][0][0];
        const short* vb = &vlds[t & 1][0][0];
        const short* krow0 = kb + q32 * 64;
        const short* krow1 = kb + (32 + q32) * 64;

        // ---- QK^T: S^T[k][q], two 32-k chunks ----
        f32x16 s0v = {}, s1v = {};
#pragma unroll
        for (int jd = 0; jd < 4; ++jd) {
            int col = ((jd * 32 + hi * 16) ^ swz) >> 1;
            bf16x8 k0 = *(const bf16x8*)(krow0 + col);
            bf16x8 k1 = *(const bf16x8*)(krow1 + col);
            s0v = __builtin_amdgcn_mfma_f32_32x32x16_bf16(k0, qf[jd], s0v, 0, 0, 0);
            s1v = __builtin_amdgcn_mfma_f32_32x32x16_bf16(k1, qf[jd], s1v, 0, 0, 0);
        }

        // ---- online softmax (log2 domain), max3-fused reduce ----
        float pm = fmaxf(s0v[0], s0v[1]);
#pragma unroll
        for (int r = 2; r < 16; r += 2) pm = fmaxf(pm, fmaxf(s0v[r], s0v[r + 1]));
#pragma unroll
        for (int r = 0; r < 16; r += 2) pm = fmaxf(pm, fmaxf(s1v[r], s1v[r + 1]));
        pm = fmaxf(pm, __shfl_xor(pm, 32));

        // defer-max: only rescale when the running max grew by > 10 (log2)
        if (!__all(pm <= mrun + 10.0f)) {
            float mn = fmaxf(mrun, pm);
            float al = exp2f(mrun - mn);
            mrun = mn;
#pragma unroll
            for (int r = 0; r < 16; ++r) { oacc0[r] *= al; oacc1[r] *= al; }
            sacc[0] *= al;
        }

#pragma unroll
        for (int r = 0; r < 16; ++r) {
            s0v[r] = exp2f(s0v[r] - mrun);
            s1v[r] = exp2f(s1v[r] - mrun);
        }

        // ---- PV: O^T[d][q] += Vt·P^T; P B-frag via cvt_pk + permlane32_swap ----
        const short* vrow0 = vb + q32 * 64;
        const short* vrow1 = vb + (32 + q32) * 64;
#pragma unroll
        for (int kc = 0; kc < 4; ++kc) {
            const f32x16& sv = (kc < 2) ? s0v : s1v;
            const int base = (kc & 1) * 8;
            unsigned A0 = pack2(sv[base + 0], sv[base + 1]);
            unsigned A1 = pack2(sv[base + 2], sv[base + 3]);
            unsigned A2 = pack2(sv[base + 4], sv[base + 5]);
            unsigned A3 = pack2(sv[base + 6], sv[base + 7]);
            asm volatile("v_permlane32_swap_b32 %0, %1" : "+v"(A0), "+v"(A2));
            asm volatile("v_permlane32_swap_b32 %0, %1" : "+v"(A1), "+v"(A3));
            union { bf16x8 v; unsigned u[4]; } pf;
            pf.u[0] = A0; pf.u[1] = A1; pf.u[2] = A2; pf.u[3] = A3;
            int col = ((kc * 32 + hi * 16) ^ swz) >> 1;
            bf16x8 v0 = *(const bf16x8*)(vrow0 + col);
            bf16x8 v1 = *(const bf16x8*)(vrow1 + col);
            oacc0 = __builtin_amdgcn_mfma_f32_32x32x16_bf16(v0, pf.v, oacc0, 0, 0, 0);
            oacc1 = __builtin_amdgcn_mfma_f32_32x32x16_bf16(v1, pf.v, oacc1, 0, 0, 0);
            sacc  = __builtin_amdgcn_mfma_f32_32x32x16_bf16(ones, pf.v, sacc, 0, 0, 0);
        }

        if (t < SLEN / 64 - 1) {
            asm volatile("s_waitcnt lgkmcnt(0)" ::: "memory");
            BAR();
        }
    }

    // ---- epilogue: O^T/l -> aout [b][s][c] bf16 ----
    float inv = 1.f / sacc[0];
    int b = bh >> 2, h = bh & 3;
    short* ob = aout + ((size_t)b * SLEN + q0 + q32) * CIN + h * HD;
#pragma unroll
    for (int g4 = 0; g4 < 4; ++g4) {
        uint2 st0, st1;
        st0.x = pack2(oacc0[4 * g4 + 0] * inv, oacc0[4 * g4 + 1] * inv);
        st0.y = pack2(oacc0[4 * g4 + 2] * inv, oacc0[4 * g4 + 3] * inv);
        st1.x = pack2(oacc1[4 * g4 + 0] * inv, oacc1[4 * g4 + 1] * inv);
        st1.y = pack2(oacc1[4 * g4 + 2] * inv, oacc1[4 * g4 + 3] * inv);
        *(uint2*)(ob + 8 * g4 + 4 * hi) = st0;
        *(uint2*)(ob + 32 + 8 * g4 + 4 * hi) = st1;
    }
#undef LOADREG
#undef WRITELDS
#undef BAR
}

// ---------------- kernel C: proj GEMM + BN + SiLU -> fp32 out ----------------
__launch_bounds__(256)
__global__ void k_proj(const short* __restrict__ aout, const short* __restrict__ wbf,
                       const float* __restrict__ g, const float* __restrict__ be,
                       const float* __restrict__ mu, const float* __restrict__ va,
                       float* __restrict__ out) {
    int wv = threadIdx.x >> 6, l = threadIdx.x & 63, lr = l & 15, lg = l >> 4;
    int b = blockIdx.z;
    int s0 = blockIdx.x * 128 + wv * 32;
    int o0 = blockIdx.y * 64;
    f32x4 acc[2][4] = {};
    const short* aptr = aout + ((size_t)b * SLEN + s0 + lr) * CIN + lg * 8;
    const short* bptr = wbf + (size_t)(o0 + lr) * CIN + lg * 8;
#pragma unroll
    for (int k0 = 0; k0 < CIN; k0 += 32) {
        bf16x8 a0 = *(const bf16x8*)(aptr + k0);
        bf16x8 a1 = *(const bf16x8*)(aptr + 16 * CIN + k0);
#pragma unroll
        for (int oj = 0; oj < 4; oj++) {
            bf16x8 bb = *(const bf16x8*)(bptr + oj * 16 * CIN + k0);
            acc[0][oj] = __builtin_amdgcn_mfma_f32_16x16x32_bf16(a0, bb, acc[0][oj], 0, 0, 0);
            acc[1][oj] = __builtin_amdgcn_mfma_f32_16x16x32_bf16(a1, bb, acc[1][oj], 0, 0, 0);
        }
    }
#pragma unroll
    for (int oj = 0; oj < 4; oj++) {
        int o = o0 + oj * 16 + lr;
        float sc = g[o] * rsqrtf(va[o] + 1e-5f);
        float sh = be[o] - mu[o] * sc;
#pragma unroll
        for (int qi = 0; qi < 2; qi++) {
            float4 st;
            float* stp = &st.x;
#pragma unroll
            for (int i = 0; i < 4; i++) {
                float y = acc[qi][oj][i] * sc + sh;
                stp[i] = y / (1.f + __expf(-y));
            }
            int s = s0 + qi * 16 + lg * 4;
            *reinterpret_cast<float4*>(out + ((size_t)b * CIN + o) * SLEN + s) = st;
        }
    }
}

extern "C" void kernel_launch(void* const* d_in, const int* in_sizes, int n_in,
                              void* d_out, int out_size, void* d_ws, size_t ws_size,
                              hipStream_t stream) {
    const float* x    = (const float*)d_in[0];
    const float* qkvw = (const float*)d_in[1];
    const float* qg   = (const float*)d_in[2];
    const float* qbe  = (const float*)d_in[3];
    const float* qmu  = (const float*)d_in[4];
    const float* qva  = (const float*)d_in[5];
    const float* pw   = (const float*)d_in[6];
    const float* pg   = (const float*)d_in[7];
    const float* pbe  = (const float*)d_in[8];
    const float* pmu  = (const float*)d_in[9];
    const float* pva  = (const float*)d_in[10];
    float* out = (float*)d_out;

    char* ws = (char*)d_ws;
    short* xT       = (short*)(ws);                 // 8,388,608 B
    short* qkvw_bf  = (short*)(ws + 8388608);       //   393,216 B
    short* projw_bf = (short*)(ws + 8781824);       //   131,072 B
    short* Qb       = (short*)(ws + 8912896);       // 8,388,608 B
    short* Kb       = (short*)(ws + 17301504);      // 8,388,608 B
    short* Vt       = (short*)(ws + 25690112);      // 8,388,608 B
    short* aout     = (short*)(ws + 34078720);      // 8,388,608 B

    k_convert_w<<<768, 256, 0, stream>>>(qkvw, pw, qkvw_bf, projw_bf);
    k_transpose_x<<<dim3(128, 8, 4), 256, 0, stream>>>(x, xT);
    k_qkv<<<dim3(32, 12, 4), 256, 0, stream>>>(xT, qkvw_bf, qg, qbe, qmu, qva, Qb, Kb, Vt);
    k_attn<<<dim3(32, 16), 256, 0, stream>>>(Qb, Kb, Vt, aout);
    k_proj<<<dim3(32, 4, 4), 256, 0, stream>>>(aout, projw_bf, pg, pbe, pmu, pva, out);
}

// Round 4
// 173.445 us; speedup vs baseline: 2.2240x; 1.1892x over previous
//
#include <hip/hip_runtime.h>
#include <hip/hip_bf16.h>
#include <math.h>

#define SLEN 4096
#define CIN 256
#define C3 768
#define NH 4
#define HD 64
#define BATCH 4

typedef __attribute__((ext_vector_type(8))) short bf16x8;
typedef __attribute__((ext_vector_type(4))) float f32x4;
typedef __attribute__((ext_vector_type(16))) float f32x16;

__device__ __forceinline__ short f2bf(float f) {
    union { float f; unsigned u; } v; v.f = f;
    unsigned r = v.u + 0x7fff + ((v.u >> 16) & 1);
    return (short)(r >> 16);
}

// single-instruction packed f32->bf16 (RNE) — no builtin on gfx950, inline asm per T12
__device__ __forceinline__ unsigned cvt_pk(float lo, float hi) {
    unsigned r;
    asm("v_cvt_pk_bf16_f32 %0, %1, %2" : "=v"(r) : "v"(lo), "v"(hi));
    return r;
}

// ---------------- kernel W: convert weights to bf16 ----------------
__global__ void k_convert_w(const float* __restrict__ qkvw, const float* __restrict__ projw,
                            short* __restrict__ qkvw_bf, short* __restrict__ projw_bf) {
    int i = blockIdx.x * 256 + threadIdx.x;
    if (i < C3 * CIN) qkvw_bf[i] = f2bf(qkvw[i]);
    if (i < CIN * CIN) projw_bf[i] = f2bf(projw[i]);
}

// ---------------- kernel T: x [b][c][s] f32 -> xT [b][s][c] bf16 ----------------
__global__ void k_transpose_x(const float* __restrict__ x, short* __restrict__ xT) {
    __shared__ float t[32][33];
    int b = blockIdx.z;
    int c0 = blockIdx.y * 32, s0 = blockIdx.x * 32;
    int tid = threadIdx.x;
    int r = tid >> 3, c4 = (tid & 7) * 4;
    const float* src = x + ((size_t)b * CIN + c0 + r) * SLEN + s0 + c4;
    float4 v = *reinterpret_cast<const float4*>(src);
    t[r][c4 + 0] = v.x; t[r][c4 + 1] = v.y; t[r][c4 + 2] = v.z; t[r][c4 + 3] = v.w;
    __syncthreads();
    int s_r = tid >> 3, cc = (tid & 7) * 4;
    short4 o = make_short4(f2bf(t[cc + 0][s_r]), f2bf(t[cc + 1][s_r]),
                           f2bf(t[cc + 2][s_r]), f2bf(t[cc + 3][s_r]));
    *reinterpret_cast<short4*>(xT + ((size_t)b * SLEN + s0 + s_r) * CIN + c0 + cc) = o;
}

// ---------------- kernel A: QKV GEMM + BN + SiLU -> Q, K, Vt (bf16) ----------------
// Q,K: [bh][s][d]; Vt: [bh][d][s]. Q pre-scaled by hd^-0.5 * log2(e).
__launch_bounds__(256)
__global__ void k_qkv(const short* __restrict__ xT, const short* __restrict__ wbf,
                      const float* __restrict__ g, const float* __restrict__ be,
                      const float* __restrict__ mu, const float* __restrict__ va,
                      short* __restrict__ Q, short* __restrict__ Kb, short* __restrict__ Vt) {
    int wv = threadIdx.x >> 6, l = threadIdx.x & 63, lr = l & 15, lg = l >> 4;
    int b = blockIdx.z;
    int s0 = blockIdx.x * 128 + wv * 32;
    int o0 = blockIdx.y * 64;
    f32x4 acc[2][4] = {};
    const short* aptr = xT + ((size_t)b * SLEN + s0 + lr) * CIN + lg * 8;
    const short* bptr = wbf + (size_t)(o0 + lr) * CIN + lg * 8;
#pragma unroll
    for (int k0 = 0; k0 < CIN; k0 += 32) {
        bf16x8 a0 = *(const bf16x8*)(aptr + k0);
        bf16x8 a1 = *(const bf16x8*)(aptr + 16 * CIN + k0);
#pragma unroll
        for (int oj = 0; oj < 4; oj++) {
            bf16x8 bb = *(const bf16x8*)(bptr + oj * 16 * CIN + k0);
            acc[0][oj] = __builtin_amdgcn_mfma_f32_16x16x32_bf16(a0, bb, acc[0][oj], 0, 0, 0);
            acc[1][oj] = __builtin_amdgcn_mfma_f32_16x16x32_bf16(a1, bb, acc[1][oj], 0, 0, 0);
        }
    }
    int which = o0 >> 8;          // uniform per block
    int h = (o0 & 255) >> 6;      // uniform per block
    int bh = b * NH + h;
    const float QSC = 0.125f * 1.44269504088896f;
#pragma unroll
    for (int oj = 0; oj < 4; oj++) {
        int o = o0 + oj * 16 + lr;
        float sc = g[o] * rsqrtf(va[o] + 1e-5f);
        float sh = be[o] - mu[o] * sc;
        int d = o & 63;
#pragma unroll
        for (int qi = 0; qi < 2; qi++) {
#pragma unroll
            for (int i = 0; i < 4; i++) {
                float y = acc[qi][oj][i] * sc + sh;
                float z = y / (1.f + __expf(-y));
                int s = s0 + qi * 16 + lg * 4 + i;
                if (which == 0) {
                    Q[((size_t)bh * SLEN + s) * HD + d] = f2bf(z * QSC);
                } else if (which == 1) {
                    Kb[((size_t)bh * SLEN + s) * HD + d] = f2bf(z);
                } else {
                    Vt[((size_t)bh * HD + d) * SLEN + s] = f2bf(z);
                }
            }
        }
    }
}

// ---------------- kernel ATTN: flash attention, swapped-QK^T in-register softmax ----
// 4 waves/block, 32 q-rows/wave, KVBLK=64, double-buffered K/Vt in LDS (XOR-swizzled).
// S^T = mfma_32x32x16(K, Q): lane holds 32 P values for q = lane&31 (k split by hi=lane>>5).
// Row-sum via MFMA(ones, P); P-frag assembly via v_cvt_pk_bf16_f32 + v_permlane32_swap;
// defer-max rescale; raw v_exp_f32 (args <= 0, HW-exact).
__launch_bounds__(256)
__global__ void k_attn(const short* __restrict__ Q, const short* __restrict__ Kg,
                       const short* __restrict__ Vg, short* __restrict__ aout) {
    __shared__ __align__(16) short klds[2][64][64];
    __shared__ __align__(16) short vlds[2][64][64];
    int tid = threadIdx.x;
    int wv = tid >> 6, l = tid & 63;
    int q32 = l & 31;           // q within wave tile (and k-row / d-row for A-frags)
    int hi  = l >> 5;
    int bh = blockIdx.y;
    int q0 = blockIdx.x * 128 + wv * 32;

    const short* kg = Kg + (size_t)bh * SLEN * HD;
    const short* vg = Vg + (size_t)bh * HD * SLEN;

    // Q B-fragments: rows q=lane&31, frag jd holds d = jd*16 + hi*8 + 0..7
    bf16x8 qf[4];
    {
        const short* qb = Q + ((size_t)bh * SLEN + q0 + q32) * HD + hi * 8;
        qf[0] = *(const bf16x8*)(qb);
        qf[1] = *(const bf16x8*)(qb + 16);
        qf[2] = *(const bf16x8*)(qb + 32);
        qf[3] = *(const bf16x8*)(qb + 48);
    }

    // ones A-fragment for the row-sum MFMA
    bf16x8 ones;
#pragma unroll
    for (int e = 0; e < 8; ++e) ones[e] = (short)0x3F80;

    f32x16 oacc0 = {}, oacc1 = {}, sacc = {};
    float mrun = -1e30f;

    // staging geometry: wave wv stages rows wv*16..wv*16+15 (two 8-row groups)
    int srow = wv * 16 + (l >> 3);
    int gs = l & 7;
    int swcol = (gs ^ (l >> 3)) * 8;   // swizzled col (shorts), row&7 == l>>3
    int4 rK0, rK1, rV0, rV1;

#define LOADREG(t) do { \
    const short* kgt = kg + ((size_t)(t) * 64 + srow) * HD + gs * 8; \
    rK0 = *(const int4*)(kgt); \
    rK1 = *(const int4*)(kgt + 8 * HD); \
    const short* vgt = vg + (size_t)srow * SLEN + (t) * 64 + gs * 8; \
    rV0 = *(const int4*)(vgt); \
    rV1 = *(const int4*)(vgt + 8 * SLEN); \
} while (0)

#define WRITELDS(bufb) do { \
    *(int4*)(&klds[bufb][srow][swcol]) = rK0; \
    *(int4*)(&klds[bufb][srow + 8][swcol]) = rK1; \
    *(int4*)(&vlds[bufb][srow][swcol]) = rV0; \
    *(int4*)(&vlds[bufb][srow + 8][swcol]) = rV1; \
} while (0)

#define BAR() do { asm volatile("" ::: "memory"); __builtin_amdgcn_s_barrier(); asm volatile("" ::: "memory"); } while (0)

    LOADREG(0);
    WRITELDS(0);
    LOADREG(1);
    asm volatile("s_waitcnt lgkmcnt(0)" ::: "memory");
    BAR();

    const int swz = (l & 7) << 4;  // byte-XOR swizzle term

    for (int t = 0; t < SLEN / 64; ++t) {
        if (t < SLEN / 64 - 1) {
            WRITELDS((t + 1) & 1);             // stage tile t+1 into idle buffer
            if (t + 2 < SLEN / 64) LOADREG(t + 2);
        }

        const short* kb = &klds[t & 1][0][0];
        const short* vb = &vlds[t & 1][0][0];
        const short* krow0 = kb + q32 * 64;
        const short* krow1 = kb + (32 + q32) * 64;

        // ---- QK^T: S^T[k][q], two 32-k chunks ----
        f32x16 s0v = {}, s1v = {};
#pragma unroll
        for (int jd = 0; jd < 4; ++jd) {
            int col = ((jd * 32 + hi * 16) ^ swz) >> 1;
            bf16x8 k0 = *(const bf16x8*)(krow0 + col);
            bf16x8 k1 = *(const bf16x8*)(krow1 + col);
            s0v = __builtin_amdgcn_mfma_f32_32x32x16_bf16(k0, qf[jd], s0v, 0, 0, 0);
            s1v = __builtin_amdgcn_mfma_f32_32x32x16_bf16(k1, qf[jd], s1v, 0, 0, 0);
        }

        // ---- online softmax (log2 domain), max3-fused reduce ----
        float pm = fmaxf(s0v[0], s0v[1]);
#pragma unroll
        for (int r = 2; r < 16; r += 2) pm = fmaxf(pm, fmaxf(s0v[r], s0v[r + 1]));
#pragma unroll
        for (int r = 0; r < 16; r += 2) pm = fmaxf(pm, fmaxf(s1v[r], s1v[r + 1]));
        pm = fmaxf(pm, __shfl_xor(pm, 32));

        // defer-max: only rescale when the running max grew by > 10 (log2)
        if (!__all(pm <= mrun + 10.0f)) {
            float mn = fmaxf(mrun, pm);
            float al = __builtin_amdgcn_exp2f(mrun - mn);
            mrun = mn;
#pragma unroll
            for (int r = 0; r < 16; ++r) { oacc0[r] *= al; oacc1[r] *= al; }
            sacc[0] *= al;
        }

#pragma unroll
        for (int r = 0; r < 16; ++r) {
            s0v[r] = __builtin_amdgcn_exp2f(s0v[r] - mrun);
            s1v[r] = __builtin_amdgcn_exp2f(s1v[r] - mrun);
        }

        // ---- PV: O^T[d][q] += Vt·P^T; P B-frag via cvt_pk + permlane32_swap ----
        const short* vrow0 = vb + q32 * 64;
        const short* vrow1 = vb + (32 + q32) * 64;
#pragma unroll
        for (int kc = 0; kc < 4; ++kc) {
            const f32x16& sv = (kc < 2) ? s0v : s1v;
            const int base = (kc & 1) * 8;
            unsigned A0 = cvt_pk(sv[base + 0], sv[base + 1]);
            unsigned A1 = cvt_pk(sv[base + 2], sv[base + 3]);
            unsigned A2 = cvt_pk(sv[base + 4], sv[base + 5]);
            unsigned A3 = cvt_pk(sv[base + 6], sv[base + 7]);
            asm volatile("v_permlane32_swap_b32 %0, %1" : "+v"(A0), "+v"(A2));
            asm volatile("v_permlane32_swap_b32 %0, %1" : "+v"(A1), "+v"(A3));
            union { bf16x8 v; unsigned u[4]; } pf;
            pf.u[0] = A0; pf.u[1] = A1; pf.u[2] = A2; pf.u[3] = A3;
            int col = ((kc * 32 + hi * 16) ^ swz) >> 1;
            bf16x8 v0 = *(const bf16x8*)(vrow0 + col);
            bf16x8 v1 = *(const bf16x8*)(vrow1 + col);
            oacc0 = __builtin_amdgcn_mfma_f32_32x32x16_bf16(v0, pf.v, oacc0, 0, 0, 0);
            oacc1 = __builtin_amdgcn_mfma_f32_32x32x16_bf16(v1, pf.v, oacc1, 0, 0, 0);
            sacc  = __builtin_amdgcn_mfma_f32_32x32x16_bf16(ones, pf.v, sacc, 0, 0, 0);
        }

        if (t < SLEN / 64 - 1) {
            asm volatile("s_waitcnt lgkmcnt(0)" ::: "memory");
            BAR();
        }
    }

    // ---- epilogue: O^T/l -> aout [b][s][c] bf16 ----
    float inv = 1.f / sacc[0];
    int b = bh >> 2, h = bh & 3;
    short* ob = aout + ((size_t)b * SLEN + q0 + q32) * CIN + h * HD;
#pragma unroll
    for (int g4 = 0; g4 < 4; ++g4) {
        uint2 st0, st1;
        st0.x = cvt_pk(oacc0[4 * g4 + 0] * inv, oacc0[4 * g4 + 1] * inv);
        st0.y = cvt_pk(oacc0[4 * g4 + 2] * inv, oacc0[4 * g4 + 3] * inv);
        st1.x = cvt_pk(oacc1[4 * g4 + 0] * inv, oacc1[4 * g4 + 1] * inv);
        st1.y = cvt_pk(oacc1[4 * g4 + 2] * inv, oacc1[4 * g4 + 3] * inv);
        *(uint2*)(ob + 8 * g4 + 4 * hi) = st0;
        *(uint2*)(ob + 32 + 8 * g4 + 4 * hi) = st1;
    }
#undef LOADREG
#undef WRITELDS
#undef BAR
}

// ---------------- kernel C: proj GEMM + BN + SiLU -> fp32 out ----------------
__launch_bounds__(256)
__global__ void k_proj(const short* __restrict__ aout, const short* __restrict__ wbf,
                       const float* __restrict__ g, const float* __restrict__ be,
                       const float* __restrict__ mu, const float* __restrict__ va,
                       float* __restrict__ out) {
    int wv = threadIdx.x >> 6, l = threadIdx.x & 63, lr = l & 15, lg = l >> 4;
    int b = blockIdx.z;
    int s0 = blockIdx.x * 128 + wv * 32;
    int o0 = blockIdx.y * 64;
    f32x4 acc[2][4] = {};
    const short* aptr = aout + ((size_t)b * SLEN + s0 + lr) * CIN + lg * 8;
    const short* bptr = wbf + (size_t)(o0 + lr) * CIN + lg * 8;
#pragma unroll
    for (int k0 = 0; k0 < CIN; k0 += 32) {
        bf16x8 a0 = *(const bf16x8*)(aptr + k0);
        bf16x8 a1 = *(const bf16x8*)(aptr + 16 * CIN + k0);
#pragma unroll
        for (int oj = 0; oj < 4; oj++) {
            bf16x8 bb = *(const bf16x8*)(bptr + oj * 16 * CIN + k0);
            acc[0][oj] = __builtin_amdgcn_mfma_f32_16x16x32_bf16(a0, bb, acc[0][oj], 0, 0, 0);
            acc[1][oj] = __builtin_amdgcn_mfma_f32_16x16x32_bf16(a1, bb, acc[1][oj], 0, 0, 0);
        }
    }
#pragma unroll
    for (int oj = 0; oj < 4; oj++) {
        int o = o0 + oj * 16 + lr;
        float sc = g[o] * rsqrtf(va[o] + 1e-5f);
        float sh = be[o] - mu[o] * sc;
#pragma unroll
        for (int qi = 0; qi < 2; qi++) {
            float4 st;
            float* stp = &st.x;
#pragma unroll
            for (int i = 0; i < 4; i++) {
                float y = acc[qi][oj][i] * sc + sh;
                stp[i] = y / (1.f + __expf(-y));
            }
            int s = s0 + qi * 16 + lg * 4;
            *reinterpret_cast<float4*>(out + ((size_t)b * CIN + o) * SLEN + s) = st;
        }
    }
}

extern "C" void kernel_launch(void* const* d_in, const int* in_sizes, int n_in,
                              void* d_out, int out_size, void* d_ws, size_t ws_size,
                              hipStream_t stream) {
    const float* x    = (const float*)d_in[0];
    const float* qkvw = (const float*)d_in[1];
    const float* qg   = (const float*)d_in[2];
    const float* qbe  = (const float*)d_in[3];
    const float* qmu  = (const float*)d_in[4];
    const float* qva  = (const float*)d_in[5];
    const float* pw   = (const float*)d_in[6];
    const float* pg   = (const float*)d_in[7];
    const float* pbe  = (const float*)d_in[8];
    const float* pmu  = (const float*)d_in[9];
    const float* pva  = (const float*)d_in[10];
    float* out = (float*)d_out;

    char* ws = (char*)d_ws;
    short* xT       = (short*)(ws);                 // 8,388,608 B
    short* qkvw_bf  = (short*)(ws + 8388608);       //   393,216 B
    short* projw_bf = (short*)(ws + 8781824);       //   131,072 B
    short* Qb       = (short*)(ws + 8912896);       // 8,388,608 B
    short* Kb       = (short*)(ws + 17301504);      // 8,388,608 B
    short* Vt       = (short*)(ws + 25690112);      // 8,388,608 B
    short* aout     = (short*)(ws + 34078720);      // 8,388,608 B

    k_convert_w<<<768, 256, 0, stream>>>(qkvw, pw, qkvw_bf, projw_bf);
    k_transpose_x<<<dim3(128, 8, 4), 256, 0, stream>>>(x, xT);
    k_qkv<<<dim3(32, 12, 4), 256, 0, stream>>>(xT, qkvw_bf, qg, qbe, qmu, qva, Qb, Kb, Vt);
    k_attn<<<dim3(32, 16), 256, 0, stream>>>(Qb, Kb, Vt, aout);
    k_proj<<<dim3(32, 4, 4), 256, 0, stream>>>(aout, projw_bf, pg, pbe, pmu, pva, out);
}

// Round 5
// 167.465 us; speedup vs baseline: 2.3034x; 1.0357x over previous
//
#include <hip/hip_runtime.h>
#include <hip/hip_bf16.h>
#include <math.h>

#define SLEN 4096
#define CIN 256
#define C3 768
#define NH 4
#define HD 64
#define BATCH 4

typedef __attribute__((ext_vector_type(8))) short bf16x8;
typedef __attribute__((ext_vector_type(4))) float f32x4;
typedef __attribute__((ext_vector_type(16))) float f32x16;

__device__ __forceinline__ short f2bf(float f) {
    union { float f; unsigned u; } v; v.f = f;
    unsigned r = v.u + 0x7fff + ((v.u >> 16) & 1);
    return (short)(r >> 16);
}

// single-instruction packed f32->bf16 (RNE) — no builtin on gfx950, inline asm per T12
__device__ __forceinline__ unsigned cvt_pk(float lo, float hi) {
    unsigned r;
    asm("v_cvt_pk_bf16_f32 %0, %1, %2" : "=v"(r) : "v"(lo), "v"(hi));
    return r;
}

// ---------------- kernel W: convert weights to bf16 ----------------
__global__ void k_convert_w(const float* __restrict__ qkvw, const float* __restrict__ projw,
                            short* __restrict__ qkvw_bf, short* __restrict__ projw_bf) {
    int i = blockIdx.x * 256 + threadIdx.x;
    if (i < C3 * CIN) qkvw_bf[i] = f2bf(qkvw[i]);
    if (i < CIN * CIN) projw_bf[i] = f2bf(projw[i]);
}

// ---------------- kernel T: x [b][c][s] f32 -> xT [b][s][c] bf16 ----------------
__global__ void k_transpose_x(const float* __restrict__ x, short* __restrict__ xT) {
    __shared__ float t[32][33];
    int b = blockIdx.z;
    int c0 = blockIdx.y * 32, s0 = blockIdx.x * 32;
    int tid = threadIdx.x;
    int r = tid >> 3, c4 = (tid & 7) * 4;
    const float* src = x + ((size_t)b * CIN + c0 + r) * SLEN + s0 + c4;
    float4 v = *reinterpret_cast<const float4*>(src);
    t[r][c4 + 0] = v.x; t[r][c4 + 1] = v.y; t[r][c4 + 2] = v.z; t[r][c4 + 3] = v.w;
    __syncthreads();
    int s_r = tid >> 3, cc = (tid & 7) * 4;
    short4 o = make_short4(f2bf(t[cc + 0][s_r]), f2bf(t[cc + 1][s_r]),
                           f2bf(t[cc + 2][s_r]), f2bf(t[cc + 3][s_r]));
    *reinterpret_cast<short4*>(xT + ((size_t)b * SLEN + s0 + s_r) * CIN + c0 + cc) = o;
}

// ---------------- kernel A: QKV GEMM + BN + SiLU -> Q, K, Vt (bf16) ----------------
// Q,K: [bh][s][d]; Vt: [bh][d][s]. Q pre-scaled by hd^-0.5 * log2(e).
__launch_bounds__(256)
__global__ void k_qkv(const short* __restrict__ xT, const short* __restrict__ wbf,
                      const float* __restrict__ g, const float* __restrict__ be,
                      const float* __restrict__ mu, const float* __restrict__ va,
                      short* __restrict__ Q, short* __restrict__ Kb, short* __restrict__ Vt) {
    int wv = threadIdx.x >> 6, l = threadIdx.x & 63, lr = l & 15, lg = l >> 4;
    int b = blockIdx.z;
    int s0 = blockIdx.x * 128 + wv * 32;
    int o0 = blockIdx.y * 64;
    f32x4 acc[2][4] = {};
    const short* aptr = xT + ((size_t)b * SLEN + s0 + lr) * CIN + lg * 8;
    const short* bptr = wbf + (size_t)(o0 + lr) * CIN + lg * 8;
#pragma unroll
    for (int k0 = 0; k0 < CIN; k0 += 32) {
        bf16x8 a0 = *(const bf16x8*)(aptr + k0);
        bf16x8 a1 = *(const bf16x8*)(aptr + 16 * CIN + k0);
#pragma unroll
        for (int oj = 0; oj < 4; oj++) {
            bf16x8 bb = *(const bf16x8*)(bptr + oj * 16 * CIN + k0);
            acc[0][oj] = __builtin_amdgcn_mfma_f32_16x16x32_bf16(a0, bb, acc[0][oj], 0, 0, 0);
            acc[1][oj] = __builtin_amdgcn_mfma_f32_16x16x32_bf16(a1, bb, acc[1][oj], 0, 0, 0);
        }
    }
    int which = o0 >> 8;          // uniform per block
    int h = (o0 & 255) >> 6;      // uniform per block
    int bh = b * NH + h;
    const float QSC = 0.125f * 1.44269504088896f;
#pragma unroll
    for (int oj = 0; oj < 4; oj++) {
        int o = o0 + oj * 16 + lr;
        float sc = g[o] * rsqrtf(va[o] + 1e-5f);
        float sh = be[o] - mu[o] * sc;
        int d = o & 63;
#pragma unroll
        for (int qi = 0; qi < 2; qi++) {
#pragma unroll
            for (int i = 0; i < 4; i++) {
                float y = acc[qi][oj][i] * sc + sh;
                float z = y / (1.f + __expf(-y));
                int s = s0 + qi * 16 + lg * 4 + i;
                if (which == 0) {
                    Q[((size_t)bh * SLEN + s) * HD + d] = f2bf(z * QSC);
                } else if (which == 1) {
                    Kb[((size_t)bh * SLEN + s) * HD + d] = f2bf(z);
                } else {
                    Vt[((size_t)bh * HD + d) * SLEN + s] = f2bf(z);
                }
            }
        }
    }
}

// ---------------- kernel ATTN: flash attention, pipelined swapped-QK^T ----
// 4 waves/block, 32 q-rows/wave, KVBLK=64. K double-buffered, V triple-buffered in LDS
// (XOR-swizzled). Software pipeline: iter t issues QK(t) into fresh S-regs, then runs
// softmax+PV of tile t-1 — QK MFMAs overlap prior tile's softmax VALU within the wave.
// S^T = mfma_32x32x16(K, Q): lane holds 32 P values for q = lane&31.
__launch_bounds__(256, 2)
__global__ void k_attn(const short* __restrict__ Q, const short* __restrict__ Kg,
                       const short* __restrict__ Vg, short* __restrict__ aout) {
    __shared__ __align__(16) short klds[2][64][64];
    __shared__ __align__(16) short vlds[3][64][64];
    int tid = threadIdx.x;
    int wv = tid >> 6, l = tid & 63;
    int q32 = l & 31;           // q within wave tile (and k-row / d-row for A-frags)
    int hi  = l >> 5;
    int bh = blockIdx.y;
    int q0 = blockIdx.x * 128 + wv * 32;

    const short* kg = Kg + (size_t)bh * SLEN * HD;
    const short* vg = Vg + (size_t)bh * HD * SLEN;

    // Q B-fragments: rows q=lane&31, frag jd holds d = jd*16 + hi*8 + 0..7
    bf16x8 qf[4];
    {
        const short* qb = Q + ((size_t)bh * SLEN + q0 + q32) * HD + hi * 8;
        qf[0] = *(const bf16x8*)(qb);
        qf[1] = *(const bf16x8*)(qb + 16);
        qf[2] = *(const bf16x8*)(qb + 32);
        qf[3] = *(const bf16x8*)(qb + 48);
    }

    // ones A-fragment for the row-sum MFMA
    bf16x8 ones;
#pragma unroll
    for (int e = 0; e < 8; ++e) ones[e] = (short)0x3F80;

    f32x16 oacc0 = {}, oacc1 = {}, sacc = {};
    float mrun = -1e30f;

    // staging geometry: wave wv stages rows wv*16..wv*16+15 (two 8-row groups)
    int srow = wv * 16 + (l >> 3);
    int gs = l & 7;
    int swcol = (gs ^ (l >> 3)) * 8;   // swizzled col (shorts), row&7 == l>>3
    int4 rK0, rK1, rV0, rV1;

#define LOADREG(t) do { \
    const short* kgt = kg + ((size_t)(t) * 64 + srow) * HD + gs * 8; \
    rK0 = *(const int4*)(kgt); \
    rK1 = *(const int4*)(kgt + 8 * HD); \
    const short* vgt = vg + (size_t)srow * SLEN + (t) * 64 + gs * 8; \
    rV0 = *(const int4*)(vgt); \
    rV1 = *(const int4*)(vgt + 8 * SLEN); \
} while (0)

#define WRITELDS(kbuf, vbuf) do { \
    *(int4*)(&klds[kbuf][srow][swcol]) = rK0; \
    *(int4*)(&klds[kbuf][srow + 8][swcol]) = rK1; \
    *(int4*)(&vlds[vbuf][srow][swcol]) = rV0; \
    *(int4*)(&vlds[vbuf][srow + 8][swcol]) = rV1; \
} while (0)

#define BAR() do { asm volatile("" ::: "memory"); __builtin_amdgcn_s_barrier(); asm volatile("" ::: "memory"); } while (0)
#define WAITBAR() do { asm volatile("s_waitcnt lgkmcnt(0)" ::: "memory"); BAR(); } while (0)

    const int swz = (l & 7) << 4;  // byte-XOR swizzle term

    // QK^T for tile t -> (d0, d1)
    auto qk = [&](int t, f32x16& d0, f32x16& d1) {
        const short* kb = &klds[t & 1][0][0];
        const short* krow0 = kb + q32 * 64;
        const short* krow1 = kb + (32 + q32) * 64;
        d0 = (f32x16){}; d1 = (f32x16){};
#pragma unroll
        for (int jd = 0; jd < 4; ++jd) {
            int col = ((jd * 32 + hi * 16) ^ swz) >> 1;
            bf16x8 k0 = *(const bf16x8*)(krow0 + col);
            bf16x8 k1 = *(const bf16x8*)(krow1 + col);
            d0 = __builtin_amdgcn_mfma_f32_32x32x16_bf16(k0, qf[jd], d0, 0, 0, 0);
            d1 = __builtin_amdgcn_mfma_f32_32x32x16_bf16(k1, qf[jd], d1, 0, 0, 0);
        }
    };

    // softmax + PV for tile tt whose scores are in (s0v, s1v); V from vlds[tt % 3]
    auto smpv = [&](int tt, f32x16& s0v, f32x16& s1v) {
        // row-max, tree-reduced (4 independent partials)
        float pa = fmaxf(fmaxf(fmaxf(s0v[0], s0v[1]), fmaxf(s0v[2], s0v[3])),
                         fmaxf(fmaxf(s0v[4], s0v[5]), fmaxf(s0v[6], s0v[7])));
        float pb = fmaxf(fmaxf(fmaxf(s0v[8], s0v[9]), fmaxf(s0v[10], s0v[11])),
                         fmaxf(fmaxf(s0v[12], s0v[13]), fmaxf(s0v[14], s0v[15])));
        float pc = fmaxf(fmaxf(fmaxf(s1v[0], s1v[1]), fmaxf(s1v[2], s1v[3])),
                         fmaxf(fmaxf(s1v[4], s1v[5]), fmaxf(s1v[6], s1v[7])));
        float pd = fmaxf(fmaxf(fmaxf(s1v[8], s1v[9]), fmaxf(s1v[10], s1v[11])),
                         fmaxf(fmaxf(s1v[12], s1v[13]), fmaxf(s1v[14], s1v[15])));
        float pm = fmaxf(fmaxf(pa, pb), fmaxf(pc, pd));
        pm = fmaxf(pm, __shfl_xor(pm, 32));

        // defer-max: only rescale when the running max grew by > 10 (log2)
        if (!__all(pm <= mrun + 10.0f)) {
            float mn = fmaxf(mrun, pm);
            float al = __builtin_amdgcn_exp2f(mrun - mn);
            mrun = mn;
#pragma unroll
            for (int r = 0; r < 16; ++r) { oacc0[r] *= al; oacc1[r] *= al; }
            sacc[0] *= al;
        }

#pragma unroll
        for (int r = 0; r < 16; ++r) {
            s0v[r] = __builtin_amdgcn_exp2f(s0v[r] - mrun);
            s1v[r] = __builtin_amdgcn_exp2f(s1v[r] - mrun);
        }

        const short* vb = &vlds[tt % 3][0][0];
        const short* vrow0 = vb + q32 * 64;
        const short* vrow1 = vb + (32 + q32) * 64;
#pragma unroll
        for (int kc = 0; kc < 4; ++kc) {
            const f32x16& sv = (kc < 2) ? s0v : s1v;
            const int base = (kc & 1) * 8;
            unsigned A0 = cvt_pk(sv[base + 0], sv[base + 1]);
            unsigned A1 = cvt_pk(sv[base + 2], sv[base + 3]);
            unsigned A2 = cvt_pk(sv[base + 4], sv[base + 5]);
            unsigned A3 = cvt_pk(sv[base + 6], sv[base + 7]);
            asm volatile("v_permlane32_swap_b32 %0, %1" : "+v"(A0), "+v"(A2));
            asm volatile("v_permlane32_swap_b32 %0, %1" : "+v"(A1), "+v"(A3));
            union { bf16x8 v; unsigned u[4]; } pf;
            pf.u[0] = A0; pf.u[1] = A1; pf.u[2] = A2; pf.u[3] = A3;
            int col = ((kc * 32 + hi * 16) ^ swz) >> 1;
            bf16x8 v0 = *(const bf16x8*)(vrow0 + col);
            bf16x8 v1 = *(const bf16x8*)(vrow1 + col);
            oacc0 = __builtin_amdgcn_mfma_f32_32x32x16_bf16(v0, pf.v, oacc0, 0, 0, 0);
            oacc1 = __builtin_amdgcn_mfma_f32_32x32x16_bf16(v1, pf.v, oacc1, 0, 0, 0);
            sacc  = __builtin_amdgcn_mfma_f32_32x32x16_bf16(ones, pf.v, sacc, 0, 0, 0);
        }
    };

    f32x16 sA0, sA1, sB0, sB1;

    // prologue: stage tile 0, load tile 1
    LOADREG(0);
    WRITELDS(0, 0);
    LOADREG(1);
    WAITBAR();

    // iter 0: stage tile 1, QK(0) -> A
    WRITELDS(1, 1);
    LOADREG(2);
    qk(0, sA0, sA1);
    WAITBAR();

    // main loop, 2-unrolled (named register sets; no runtime-indexed reg arrays)
    for (int t = 1; t < 63; t += 2) {
        // iter t: stage t+1, QK(t)->B, finish t-1 (A)
        WRITELDS((t + 1) & 1, (t + 1) % 3);
        LOADREG(t + 2);
        qk(t, sB0, sB1);
        smpv(t - 1, sA0, sA1);
        WAITBAR();
        // iter t+1: stage t+2, QK(t+1)->A, finish t (B)
        WRITELDS((t + 2) & 1, (t + 2) % 3);
        if (t + 3 < 64) LOADREG(t + 3);
        qk(t + 1, sA0, sA1);
        smpv(t, sB0, sB1);
        WAITBAR();
    }

    // iter 63: QK(63)->B, finish 62 (A); then finish 63 (B)
    qk(63, sB0, sB1);
    smpv(62, sA0, sA1);
    smpv(63, sB0, sB1);

    // ---- epilogue: O^T/l -> aout [b][s][c] bf16 ----
    float inv = 1.f / sacc[0];
    int b = bh >> 2, h = bh & 3;
    short* ob = aout + ((size_t)b * SLEN + q0 + q32) * CIN + h * HD;
#pragma unroll
    for (int g4 = 0; g4 < 4; ++g4) {
        uint2 st0, st1;
        st0.x = cvt_pk(oacc0[4 * g4 + 0] * inv, oacc0[4 * g4 + 1] * inv);
        st0.y = cvt_pk(oacc0[4 * g4 + 2] * inv, oacc0[4 * g4 + 3] * inv);
        st1.x = cvt_pk(oacc1[4 * g4 + 0] * inv, oacc1[4 * g4 + 1] * inv);
        st1.y = cvt_pk(oacc1[4 * g4 + 2] * inv, oacc1[4 * g4 + 3] * inv);
        *(uint2*)(ob + 8 * g4 + 4 * hi) = st0;
        *(uint2*)(ob + 32 + 8 * g4 + 4 * hi) = st1;
    }
#undef LOADREG
#undef WRITELDS
#undef BAR
#undef WAITBAR
}

// ---------------- kernel C: proj GEMM + BN + SiLU -> fp32 out ----------------
__launch_bounds__(256)
__global__ void k_proj(const short* __restrict__ aout, const short* __restrict__ wbf,
                       const float* __restrict__ g, const float* __restrict__ be,
                       const float* __restrict__ mu, const float* __restrict__ va,
                       float* __restrict__ out) {
    int wv = threadIdx.x >> 6, l = threadIdx.x & 63, lr = l & 15, lg = l >> 4;
    int b = blockIdx.z;
    int s0 = blockIdx.x * 128 + wv * 32;
    int o0 = blockIdx.y * 64;
    f32x4 acc[2][4] = {};
    const short* aptr = aout + ((size_t)b * SLEN + s0 + lr) * CIN + lg * 8;
    const short* bptr = wbf + (size_t)(o0 + lr) * CIN + lg * 8;
#pragma unroll
    for (int k0 = 0; k0 < CIN; k0 += 32) {
        bf16x8 a0 = *(const bf16x8*)(aptr + k0);
        bf16x8 a1 = *(const bf16x8*)(aptr + 16 * CIN + k0);
#pragma unroll
        for (int oj = 0; oj < 4; oj++) {
            bf16x8 bb = *(const bf16x8*)(bptr + oj * 16 * CIN + k0);
            acc[0][oj] = __builtin_amdgcn_mfma_f32_16x16x32_bf16(a0, bb, acc[0][oj], 0, 0, 0);
            acc[1][oj] = __builtin_amdgcn_mfma_f32_16x16x32_bf16(a1, bb, acc[1][oj], 0, 0, 0);
        }
    }
#pragma unroll
    for (int oj = 0; oj < 4; oj++) {
        int o = o0 + oj * 16 + lr;
        float sc = g[o] * rsqrtf(va[o] + 1e-5f);
        float sh = be[o] - mu[o] * sc;
#pragma unroll
        for (int qi = 0; qi < 2; qi++) {
            float4 st;
            float* stp = &st.x;
#pragma unroll
            for (int i = 0; i < 4; i++) {
                float y = acc[qi][oj][i] * sc + sh;
                stp[i] = y / (1.f + __expf(-y));
            }
            int s = s0 + qi * 16 + lg * 4;
            *reinterpret_cast<float4*>(out + ((size_t)b * CIN + o) * SLEN + s) = st;
        }
    }
}

extern "C" void kernel_launch(void* const* d_in, const int* in_sizes, int n_in,
                              void* d_out, int out_size, void* d_ws, size_t ws_size,
                              hipStream_t stream) {
    const float* x    = (const float*)d_in[0];
    const float* qkvw = (const float*)d_in[1];
    const float* qg   = (const float*)d_in[2];
    const float* qbe  = (const float*)d_in[3];
    const float* qmu  = (const float*)d_in[4];
    const float* qva  = (const float*)d_in[5];
    const float* pw   = (const float*)d_in[6];
    const float* pg   = (const float*)d_in[7];
    const float* pbe  = (const float*)d_in[8];
    const float* pmu  = (const float*)d_in[9];
    const float* pva  = (const float*)d_in[10];
    float* out = (float*)d_out;

    char* ws = (char*)d_ws;
    short* xT       = (short*)(ws);                 // 8,388,608 B
    short* qkvw_bf  = (short*)(ws + 8388608);       //   393,216 B
    short* projw_bf = (short*)(ws + 8781824);       //   131,072 B
    short* Qb       = (short*)(ws + 8912896);       // 8,388,608 B
    short* Kb       = (short*)(ws + 17301504);      // 8,388,608 B
    short* Vt       = (short*)(ws + 25690112);      // 8,388,608 B
    short* aout     = (short*)(ws + 34078720);      // 8,388,608 B

    k_convert_w<<<768, 256, 0, stream>>>(qkvw, pw, qkvw_bf, projw_bf);
    k_transpose_x<<<dim3(128, 8, 4), 256, 0, stream>>>(x, xT);
    k_qkv<<<dim3(32, 12, 4), 256, 0, stream>>>(xT, qkvw_bf, qg, qbe, qmu, qva, Qb, Kb, Vt);
    k_attn<<<dim3(32, 16), 256, 0, stream>>>(Qb, Kb, Vt, aout);
    k_proj<<<dim3(32, 4, 4), 256, 0, stream>>>(aout, projw_bf, pg, pbe, pmu, pva, out);
}

// Round 6
// 163.529 us; speedup vs baseline: 2.3588x; 1.0241x over previous
//
#include <hip/hip_runtime.h>
#include <hip/hip_bf16.h>
#include <math.h>

#define SLEN 4096
#define CIN 256
#define C3 768
#define NH 4
#define HD 64
#define BATCH 4

typedef __attribute__((ext_vector_type(8))) short bf16x8;
typedef __attribute__((ext_vector_type(4))) float f32x4;
typedef __attribute__((ext_vector_type(16))) float f32x16;

__device__ __forceinline__ short f2bf(float f) {
    union { float f; unsigned u; } v; v.f = f;
    unsigned r = v.u + 0x7fff + ((v.u >> 16) & 1);
    return (short)(r >> 16);
}

// single-instruction packed f32->bf16 (RNE) — no builtin on gfx950, inline asm per T12
__device__ __forceinline__ unsigned cvt_pk(float lo, float hi) {
    unsigned r;
    asm("v_cvt_pk_bf16_f32 %0, %1, %2" : "=v"(r) : "v"(lo), "v"(hi));
    return r;
}

// ---------------- kernel W: convert weights to bf16 ----------------
__global__ void k_convert_w(const float* __restrict__ qkvw, const float* __restrict__ projw,
                            short* __restrict__ qkvw_bf, short* __restrict__ projw_bf) {
    int i = blockIdx.x * 256 + threadIdx.x;
    if (i < C3 * CIN) qkvw_bf[i] = f2bf(qkvw[i]);
    if (i < CIN * CIN) projw_bf[i] = f2bf(projw[i]);
}

// ---------------- kernel T: x [b][c][s] f32 -> xT [b][s][c] bf16 ----------------
__global__ void k_transpose_x(const float* __restrict__ x, short* __restrict__ xT) {
    __shared__ float t[32][33];
    int b = blockIdx.z;
    int c0 = blockIdx.y * 32, s0 = blockIdx.x * 32;
    int tid = threadIdx.x;
    int r = tid >> 3, c4 = (tid & 7) * 4;
    const float* src = x + ((size_t)b * CIN + c0 + r) * SLEN + s0 + c4;
    float4 v = *reinterpret_cast<const float4*>(src);
    t[r][c4 + 0] = v.x; t[r][c4 + 1] = v.y; t[r][c4 + 2] = v.z; t[r][c4 + 3] = v.w;
    __syncthreads();
    int s_r = tid >> 3, cc = (tid & 7) * 4;
    short4 o = make_short4(f2bf(t[cc + 0][s_r]), f2bf(t[cc + 1][s_r]),
                           f2bf(t[cc + 2][s_r]), f2bf(t[cc + 3][s_r]));
    *reinterpret_cast<short4*>(xT + ((size_t)b * SLEN + s0 + s_r) * CIN + c0 + cc) = o;
}

// ---------------- kernel A: QKV GEMM + BN + SiLU -> Q, K, Vt (bf16) ----------------
// Q,K: [bh][s][d]; Vt: [bh][d][s]. Q pre-scaled by hd^-0.5 * log2(e).
__launch_bounds__(256)
__global__ void k_qkv(const short* __restrict__ xT, const short* __restrict__ wbf,
                      const float* __restrict__ g, const float* __restrict__ be,
                      const float* __restrict__ mu, const float* __restrict__ va,
                      short* __restrict__ Q, short* __restrict__ Kb, short* __restrict__ Vt) {
    int wv = threadIdx.x >> 6, l = threadIdx.x & 63, lr = l & 15, lg = l >> 4;
    int b = blockIdx.z;
    int s0 = blockIdx.x * 128 + wv * 32;
    int o0 = blockIdx.y * 64;
    f32x4 acc[2][4] = {};
    const short* aptr = xT + ((size_t)b * SLEN + s0 + lr) * CIN + lg * 8;
    const short* bptr = wbf + (size_t)(o0 + lr) * CIN + lg * 8;
#pragma unroll
    for (int k0 = 0; k0 < CIN; k0 += 32) {
        bf16x8 a0 = *(const bf16x8*)(aptr + k0);
        bf16x8 a1 = *(const bf16x8*)(aptr + 16 * CIN + k0);
#pragma unroll
        for (int oj = 0; oj < 4; oj++) {
            bf16x8 bb = *(const bf16x8*)(bptr + oj * 16 * CIN + k0);
            acc[0][oj] = __builtin_amdgcn_mfma_f32_16x16x32_bf16(a0, bb, acc[0][oj], 0, 0, 0);
            acc[1][oj] = __builtin_amdgcn_mfma_f32_16x16x32_bf16(a1, bb, acc[1][oj], 0, 0, 0);
        }
    }
    int which = o0 >> 8;          // uniform per block
    int h = (o0 & 255) >> 6;      // uniform per block
    int bh = b * NH + h;
    const float QSC = 0.125f * 1.44269504088896f;
#pragma unroll
    for (int oj = 0; oj < 4; oj++) {
        int o = o0 + oj * 16 + lr;
        float sc = g[o] * rsqrtf(va[o] + 1e-5f);
        float sh = be[o] - mu[o] * sc;
        int d = o & 63;
#pragma unroll
        for (int qi = 0; qi < 2; qi++) {
#pragma unroll
            for (int i = 0; i < 4; i++) {
                float y = acc[qi][oj][i] * sc + sh;
                float z = y / (1.f + __expf(-y));
                int s = s0 + qi * 16 + lg * 4 + i;
                if (which == 0) {
                    Q[((size_t)bh * SLEN + s) * HD + d] = f2bf(z * QSC);
                } else if (which == 1) {
                    Kb[((size_t)bh * SLEN + s) * HD + d] = f2bf(z);
                } else {
                    Vt[((size_t)bh * HD + d) * SLEN + s] = f2bf(z);
                }
            }
        }
    }
}

// ---------------- kernel ATTN: flash attention, pipelined swapped-QK^T ----
// 4 waves/block, 32 q-rows/wave, KVBLK=64. K 2-buf @ lds+0, V 4-buf @ lds+16384,
// XOR-swizzled; ALL buffer indices compile-time (unroll 4) -> ds offsets in imm field.
// QK accumulators bias-initialized with -mrun (per-set bias bA/bB); defer-max rescale.
// S^T = mfma_32x32x16(K, Q): lane holds 32 P values for q = lane&31.
__launch_bounds__(256, 2)
__global__ void k_attn(const short* __restrict__ Q, const short* __restrict__ Kg,
                       const short* __restrict__ Vg, short* __restrict__ aout) {
    __shared__ __align__(16) char lds[16384 + 32768];
    int tid = threadIdx.x;
    int wv = tid >> 6, l = tid & 63;
    int q32 = l & 31;           // q within wave tile (and k-row / d-row for A-frags)
    int hi  = l >> 5;
    int bh = blockIdx.y;
    int q0 = blockIdx.x * 128 + wv * 32;

    const short* kg = Kg + (size_t)bh * SLEN * HD;
    const short* vg = Vg + (size_t)bh * HD * SLEN;

    // Q B-fragments: rows q=lane&31, frag jd holds d = jd*16 + hi*8 + 0..7
    bf16x8 qf[4];
    {
        const short* qb = Q + ((size_t)bh * SLEN + q0 + q32) * HD + hi * 8;
        qf[0] = *(const bf16x8*)(qb);
        qf[1] = *(const bf16x8*)(qb + 16);
        qf[2] = *(const bf16x8*)(qb + 32);
        qf[3] = *(const bf16x8*)(qb + 48);
    }

    // ones A-fragment for the row-sum MFMA
    bf16x8 ones;
#pragma unroll
    for (int e = 0; e < 8; ++e) ones[e] = (short)0x3F80;

    f32x16 oacc0 = {}, oacc1 = {}, sacc = {};
    float mrun = 0.0f, bA = 0.0f, bB = 0.0f;

    // staging geometry: wave wv stages rows wv*16..wv*16+15 (two 8-row groups)
    int srow = wv * 16 + (l >> 3);
    int gs = l & 7;
    int swz = (l & 7) << 4;                           // byte-XOR swizzle term
    int soff = srow * 128 + ((gs ^ (l >> 3)) << 4);   // staging byte offset in tile
    // shared per-lane read offsets (bytes within a 64x64-short tile); serve K and V
    int a0 = q32 * 128 + ((0 * 32 + hi * 16) ^ swz);
    int a1 = q32 * 128 + ((1 * 32 + hi * 16) ^ swz);
    int a2 = q32 * 128 + ((2 * 32 + hi * 16) ^ swz);
    int a3 = q32 * 128 + ((3 * 32 + hi * 16) ^ swz);

    int klane = srow * HD + gs * 8;    // shorts
    int vlane = srow * SLEN + gs * 8;  // shorts
    int4 rK0, rK1, rV0, rV1;

#define LOADREG(T) do { \
    const short* kgt = kg + (size_t)(T) * 4096 + klane; \
    rK0 = *(const int4*)(kgt); \
    rK1 = *(const int4*)(kgt + 8 * HD); \
    const short* vgt = vg + (size_t)(T) * 64 + vlane; \
    rV0 = *(const int4*)(vgt); \
    rV1 = *(const int4*)(vgt + 8 * SLEN); \
} while (0)

#define WRITELDS(KB, VB) do { \
    *(int4*)(lds + soff + (KB) * 8192) = rK0; \
    *(int4*)(lds + soff + (KB) * 8192 + 1024) = rK1; \
    *(int4*)(lds + soff + 16384 + (VB) * 8192) = rV0; \
    *(int4*)(lds + soff + 16384 + (VB) * 8192 + 1024) = rV1; \
} while (0)

#define BAR() do { asm volatile("" ::: "memory"); __builtin_amdgcn_s_barrier(); asm volatile("" ::: "memory"); } while (0)
#define WAITBAR() do { asm volatile("s_waitcnt lgkmcnt(0)" ::: "memory"); BAR(); } while (0)

#define MFMA32(A, B, C) __builtin_amdgcn_mfma_f32_32x32x16_bf16(A, B, C)

// QK^T for one tile from K buffer KB, accumulators bias-initialized with -mrun
#define QKT(KB, D0, D1, BSET) do { \
    BSET = mrun; \
    float nb_ = -mrun; \
    _Pragma("unroll") for (int r_ = 0; r_ < 16; ++r_) { D0[r_] = nb_; D1[r_] = nb_; } \
    { \
        bf16x8 k0_, k1_; \
        k0_ = *(const bf16x8*)(lds + a0 + (KB) * 8192); \
        k1_ = *(const bf16x8*)(lds + a0 + (KB) * 8192 + 4096); \
        D0 = __builtin_amdgcn_mfma_f32_32x32x16_bf16(k0_, qf[0], D0, 0, 0, 0); \
        D1 = __builtin_amdgcn_mfma_f32_32x32x16_bf16(k1_, qf[0], D1, 0, 0, 0); \
        k0_ = *(const bf16x8*)(lds + a1 + (KB) * 8192); \
        k1_ = *(const bf16x8*)(lds + a1 + (KB) * 8192 + 4096); \
        D0 = __builtin_amdgcn_mfma_f32_32x32x16_bf16(k0_, qf[1], D0, 0, 0, 0); \
        D1 = __builtin_amdgcn_mfma_f32_32x32x16_bf16(k1_, qf[1], D1, 0, 0, 0); \
        k0_ = *(const bf16x8*)(lds + a2 + (KB) * 8192); \
        k1_ = *(const bf16x8*)(lds + a2 + (KB) * 8192 + 4096); \
        D0 = __builtin_amdgcn_mfma_f32_32x32x16_bf16(k0_, qf[2], D0, 0, 0, 0); \
        D1 = __builtin_amdgcn_mfma_f32_32x32x16_bf16(k1_, qf[2], D1, 0, 0, 0); \
        k0_ = *(const bf16x8*)(lds + a3 + (KB) * 8192); \
        k1_ = *(const bf16x8*)(lds + a3 + (KB) * 8192 + 4096); \
        D0 = __builtin_amdgcn_mfma_f32_32x32x16_bf16(k0_, qf[3], D0, 0, 0, 0); \
        D1 = __builtin_amdgcn_mfma_f32_32x32x16_bf16(k1_, qf[3], D1, 0, 0, 0); \
    } \
} while (0)

// one 32-k PV chunk: scores SV[BASE..BASE+7], V cols via addr reg AK, buffer VB
#define PVKC(AK, SV, BASE, VB) do { \
    unsigned A0_ = cvt_pk(SV[(BASE) + 0], SV[(BASE) + 1]); \
    unsigned A1_ = cvt_pk(SV[(BASE) + 2], SV[(BASE) + 3]); \
    unsigned A2_ = cvt_pk(SV[(BASE) + 4], SV[(BASE) + 5]); \
    unsigned A3_ = cvt_pk(SV[(BASE) + 6], SV[(BASE) + 7]); \
    asm volatile("v_permlane32_swap_b32 %0, %1" : "+v"(A0_), "+v"(A2_)); \
    asm volatile("v_permlane32_swap_b32 %0, %1" : "+v"(A1_), "+v"(A3_)); \
    union { bf16x8 v; unsigned u[4]; } pf_; \
    pf_.u[0] = A0_; pf_.u[1] = A1_; pf_.u[2] = A2_; pf_.u[3] = A3_; \
    bf16x8 v0_ = *(const bf16x8*)(lds + (AK) + 16384 + (VB) * 8192); \
    bf16x8 v1_ = *(const bf16x8*)(lds + (AK) + 16384 + (VB) * 8192 + 4096); \
    oacc0 = __builtin_amdgcn_mfma_f32_32x32x16_bf16(v0_, pf_.v, oacc0, 0, 0, 0); \
    oacc1 = __builtin_amdgcn_mfma_f32_32x32x16_bf16(v1_, pf_.v, oacc1, 0, 0, 0); \
    sacc  = __builtin_amdgcn_mfma_f32_32x32x16_bf16(ones, pf_.v, sacc, 0, 0, 0); \
} while (0)

// softmax (biased scores: s = S - BSET) + PV from V buffer VB
#define SMPV(VB, S0, S1, BSET) do { \
    float pa_ = S0[0], pb_ = S0[8], pc_ = S1[0], pd_ = S1[8]; \
    _Pragma("unroll") for (int r_ = 1; r_ < 8; ++r_) { \
        pa_ = fmaxf(pa_, S0[r_]); pb_ = fmaxf(pb_, S0[8 + r_]); \
        pc_ = fmaxf(pc_, S1[r_]); pd_ = fmaxf(pd_, S1[8 + r_]); \
    } \
    float pms_ = fmaxf(fmaxf(pa_, pb_), fmaxf(pc_, pd_)); \
    float c1_ = pms_, c2_ = pms_; \
    asm volatile("" : "+v"(c2_)); /* force distinct register */ \
    asm volatile("v_permlane32_swap_b32 %0, %1" : "+v"(c1_), "+v"(c2_)); \
    pms_ = fmaxf(c1_, c2_); \
    float db_ = mrun - (BSET); \
    if (!__all(pms_ <= db_ + 10.0f)) { \
        float mn_ = fmaxf(mrun, pms_ + (BSET)); \
        float al_ = __builtin_amdgcn_exp2f(mrun - mn_); \
        _Pragma("unroll") for (int r_ = 0; r_ < 16; ++r_) { oacc0[r_] *= al_; oacc1[r_] *= al_; } \
        sacc[0] *= al_; \
        mrun = mn_; db_ = mn_ - (BSET); \
    } \
    if (__all(db_ == 0.0f)) { \
        _Pragma("unroll") for (int r_ = 0; r_ < 16; ++r_) { \
            S0[r_] = __builtin_amdgcn_exp2f(S0[r_]); \
            S1[r_] = __builtin_amdgcn_exp2f(S1[r_]); \
        } \
    } else { \
        _Pragma("unroll") for (int r_ = 0; r_ < 16; ++r_) { \
            S0[r_] = __builtin_amdgcn_exp2f(S0[r_] - db_); \
            S1[r_] = __builtin_amdgcn_exp2f(S1[r_] - db_); \
        } \
    } \
    PVKC(a0, S0, 0, VB); \
    PVKC(a1, S0, 8, VB); \
    PVKC(a2, S1, 0, VB); \
    PVKC(a3, S1, 8, VB); \
} while (0)

    f32x16 sA0, sA1, sB0, sB1;

    // prologue: stage tile 0 (K0,V0), load 1; stage 1 (K1,V1), load 2; QK(0)->A
    LOADREG(0);
    WRITELDS(0, 0);
    LOADREG(1);
    WAITBAR();
    WRITELDS(1, 1);
    LOADREG(2);
    QKT(0, sA0, sA1, bA);
    WAITBAR();

    // steady state: tiles 1..60, unroll 4 (all buffer indices literal)
    for (int j = 0; j < 15; ++j) {
        int t = 4 * j + 1;
        WRITELDS(0, 2); LOADREG(t + 2); QKT(1, sB0, sB1, bB); SMPV(0, sA0, sA1, bA); WAITBAR();
        WRITELDS(1, 3); LOADREG(t + 3); QKT(0, sA0, sA1, bA); SMPV(1, sB0, sB1, bB); WAITBAR();
        WRITELDS(0, 0); LOADREG(t + 4); QKT(1, sB0, sB1, bB); SMPV(2, sA0, sA1, bA); WAITBAR();
        WRITELDS(1, 1); LOADREG(t + 5); QKT(0, sA0, sA1, bA); SMPV(3, sB0, sB1, bB); WAITBAR();
    }
    // t = 61
    WRITELDS(0, 2); LOADREG(63); QKT(1, sB0, sB1, bB); SMPV(0, sA0, sA1, bA); WAITBAR();
    // t = 62
    WRITELDS(1, 3); QKT(0, sA0, sA1, bA); SMPV(1, sB0, sB1, bB); WAITBAR();
    // t = 63
    QKT(1, sB0, sB1, bB); SMPV(2, sA0, sA1, bA);
    // finish tile 63
    SMPV(3, sB0, sB1, bB);

    // ---- epilogue: O^T/l -> aout [b][s][c] bf16 ----
    float inv = 1.f / sacc[0];
    int b = bh >> 2, h = bh & 3;
    short* ob = aout + ((size_t)b * SLEN + q0 + q32) * CIN + h * HD;
#pragma unroll
    for (int g4 = 0; g4 < 4; ++g4) {
        uint2 st0, st1;
        st0.x = cvt_pk(oacc0[4 * g4 + 0] * inv, oacc0[4 * g4 + 1] * inv);
        st0.y = cvt_pk(oacc0[4 * g4 + 2] * inv, oacc0[4 * g4 + 3] * inv);
        st1.x = cvt_pk(oacc1[4 * g4 + 0] * inv, oacc1[4 * g4 + 1] * inv);
        st1.y = cvt_pk(oacc1[4 * g4 + 2] * inv, oacc1[4 * g4 + 3] * inv);
        *(uint2*)(ob + 8 * g4 + 4 * hi) = st0;
        *(uint2*)(ob + 32 + 8 * g4 + 4 * hi) = st1;
    }
#undef LOADREG
#undef WRITELDS
#undef BAR
#undef WAITBAR
#undef MFMA32
#undef QKT
#undef PVKC
#undef SMPV
}

// ---------------- kernel C: proj GEMM + BN + SiLU -> fp32 out ----------------
__launch_bounds__(256)
__global__ void k_proj(const short* __restrict__ aout, const short* __restrict__ wbf,
                       const float* __restrict__ g, const float* __restrict__ be,
                       const float* __restrict__ mu, const float* __restrict__ va,
                       float* __restrict__ out) {
    int wv = threadIdx.x >> 6, l = threadIdx.x & 63, lr = l & 15, lg = l >> 4;
    int b = blockIdx.z;
    int s0 = blockIdx.x * 128 + wv * 32;
    int o0 = blockIdx.y * 64;
    f32x4 acc[2][4] = {};
    const short* aptr = aout + ((size_t)b * SLEN + s0 + lr) * CIN + lg * 8;
    const short* bptr = wbf + (size_t)(o0 + lr) * CIN + lg * 8;
#pragma unroll
    for (int k0 = 0; k0 < CIN; k0 += 32) {
        bf16x8 a0 = *(const bf16x8*)(aptr + k0);
        bf16x8 a1 = *(const bf16x8*)(aptr + 16 * CIN + k0);
#pragma unroll
        for (int oj = 0; oj < 4; oj++) {
            bf16x8 bb = *(const bf16x8*)(bptr + oj * 16 * CIN + k0);
            acc[0][oj] = __builtin_amdgcn_mfma_f32_16x16x32_bf16(a0, bb, acc[0][oj], 0, 0, 0);
            acc[1][oj] = __builtin_amdgcn_mfma_f32_16x16x32_bf16(a1, bb, acc[1][oj], 0, 0, 0);
        }
    }
#pragma unroll
    for (int oj = 0; oj < 4; oj++) {
        int o = o0 + oj * 16 + lr;
        float sc = g[o] * rsqrtf(va[o] + 1e-5f);
        float sh = be[o] - mu[o] * sc;
#pragma unroll
        for (int qi = 0; qi < 2; qi++) {
            float4 st;
            float* stp = &st.x;
#pragma unroll
            for (int i = 0; i < 4; i++) {
                float y = acc[qi][oj][i] * sc + sh;
                stp[i] = y / (1.f + __expf(-y));
            }
            int s = s0 + qi * 16 + lg * 4;
            *reinterpret_cast<float4*>(out + ((size_t)b * CIN + o) * SLEN + s) = st;
        }
    }
}

extern "C" void kernel_launch(void* const* d_in, const int* in_sizes, int n_in,
                              void* d_out, int out_size, void* d_ws, size_t ws_size,
                              hipStream_t stream) {
    const float* x    = (const float*)d_in[0];
    const float* qkvw = (const float*)d_in[1];
    const float* qg   = (const float*)d_in[2];
    const float* qbe  = (const float*)d_in[3];
    const float* qmu  = (const float*)d_in[4];
    const float* qva  = (const float*)d_in[5];
    const float* pw   = (const float*)d_in[6];
    const float* pg   = (const float*)d_in[7];
    const float* pbe  = (const float*)d_in[8];
    const float* pmu  = (const float*)d_in[9];
    const float* pva  = (const float*)d_in[10];
    float* out = (float*)d_out;

    char* ws = (char*)d_ws;
    short* xT       = (short*)(ws);                 // 8,388,608 B
    short* qkvw_bf  = (short*)(ws + 8388608);       //   393,216 B
    short* projw_bf = (short*)(ws + 8781824);       //   131,072 B
    short* Qb       = (short*)(ws + 8912896);       // 8,388,608 B
    short* Kb       = (short*)(ws + 17301504);      // 8,388,608 B
    short* Vt       = (short*)(ws + 25690112);      // 8,388,608 B
    short* aout     = (short*)(ws + 34078720);      // 8,388,608 B

    k_convert_w<<<768, 256, 0, stream>>>(qkvw, pw, qkvw_bf, projw_bf);
    k_transpose_x<<<dim3(128, 8, 4), 256, 0, stream>>>(x, xT);
    k_qkv<<<dim3(32, 12, 4), 256, 0, stream>>>(xT, qkvw_bf, qg, qbe, qmu, qva, Qb, Kb, Vt);
    k_attn<<<dim3(32, 16), 256, 0, stream>>>(Qb, Kb, Vt, aout);
    k_proj<<<dim3(32, 4, 4), 256, 0, stream>>>(aout, projw_bf, pg, pbe, pmu, pva, out);
}

// Round 7
// 159.674 us; speedup vs baseline: 2.4158x; 1.0241x over previous
//
#include <hip/hip_runtime.h>
#include <hip/hip_bf16.h>
#include <math.h>

#define SLEN 4096
#define CIN 256
#define C3 768
#define NH 4
#define HD 64
#define BATCH 4

typedef __attribute__((ext_vector_type(8))) short bf16x8;
typedef __attribute__((ext_vector_type(4))) float f32x4;
typedef __attribute__((ext_vector_type(16))) float f32x16;

typedef const __attribute__((address_space(1))) void GVoid;
typedef __attribute__((address_space(3))) void LVoid;

__device__ __forceinline__ void gl2lds16(const void* g, void* l) {
    __builtin_amdgcn_global_load_lds((GVoid*)g, (LVoid*)l, 16, 0, 0);
}

__device__ __forceinline__ short f2bf(float f) {
    union { float f; unsigned u; } v; v.f = f;
    unsigned r = v.u + 0x7fff + ((v.u >> 16) & 1);
    return (short)(r >> 16);
}

// single-instruction packed f32->bf16 (RNE) — no builtin on gfx950, inline asm per T12
__device__ __forceinline__ unsigned cvt_pk(float lo, float hi) {
    unsigned r;
    asm("v_cvt_pk_bf16_f32 %0, %1, %2" : "=v"(r) : "v"(lo), "v"(hi));
    return r;
}

// ---------------- kernel W: convert weights to bf16 ----------------
__global__ void k_convert_w(const float* __restrict__ qkvw, const float* __restrict__ projw,
                            short* __restrict__ qkvw_bf, short* __restrict__ projw_bf) {
    int i = blockIdx.x * 256 + threadIdx.x;
    if (i < C3 * CIN) qkvw_bf[i] = f2bf(qkvw[i]);
    if (i < CIN * CIN) projw_bf[i] = f2bf(projw[i]);
}

// ---------------- kernel T: x [b][c][s] f32 -> xT [b][s][c] bf16 ----------------
__global__ void k_transpose_x(const float* __restrict__ x, short* __restrict__ xT) {
    __shared__ float t[32][33];
    int b = blockIdx.z;
    int c0 = blockIdx.y * 32, s0 = blockIdx.x * 32;
    int tid = threadIdx.x;
    int r = tid >> 3, c4 = (tid & 7) * 4;
    const float* src = x + ((size_t)b * CIN + c0 + r) * SLEN + s0 + c4;
    float4 v = *reinterpret_cast<const float4*>(src);
    t[r][c4 + 0] = v.x; t[r][c4 + 1] = v.y; t[r][c4 + 2] = v.z; t[r][c4 + 3] = v.w;
    __syncthreads();
    int s_r = tid >> 3, cc = (tid & 7) * 4;
    short4 o = make_short4(f2bf(t[cc + 0][s_r]), f2bf(t[cc + 1][s_r]),
                           f2bf(t[cc + 2][s_r]), f2bf(t[cc + 3][s_r]));
    *reinterpret_cast<short4*>(xT + ((size_t)b * SLEN + s0 + s_r) * CIN + c0 + cc) = o;
}

// ---------------- kernel A: QKV GEMM + BN + SiLU -> Q, K, Vt (bf16) ----------------
// Q,K: [bh][s][d]; Vt: [bh][d][s]. Q pre-scaled by hd^-0.5 * log2(e).
__launch_bounds__(256)
__global__ void k_qkv(const short* __restrict__ xT, const short* __restrict__ wbf,
                      const float* __restrict__ g, const float* __restrict__ be,
                      const float* __restrict__ mu, const float* __restrict__ va,
                      short* __restrict__ Q, short* __restrict__ Kb, short* __restrict__ Vt) {
    int wv = threadIdx.x >> 6, l = threadIdx.x & 63, lr = l & 15, lg = l >> 4;
    int b = blockIdx.z;
    int s0 = blockIdx.x * 128 + wv * 32;
    int o0 = blockIdx.y * 64;
    f32x4 acc[2][4] = {};
    const short* aptr = xT + ((size_t)b * SLEN + s0 + lr) * CIN + lg * 8;
    const short* bptr = wbf + (size_t)(o0 + lr) * CIN + lg * 8;
#pragma unroll
    for (int k0 = 0; k0 < CIN; k0 += 32) {
        bf16x8 a0 = *(const bf16x8*)(aptr + k0);
        bf16x8 a1 = *(const bf16x8*)(aptr + 16 * CIN + k0);
#pragma unroll
        for (int oj = 0; oj < 4; oj++) {
            bf16x8 bb = *(const bf16x8*)(bptr + oj * 16 * CIN + k0);
            acc[0][oj] = __builtin_amdgcn_mfma_f32_16x16x32_bf16(a0, bb, acc[0][oj], 0, 0, 0);
            acc[1][oj] = __builtin_amdgcn_mfma_f32_16x16x32_bf16(a1, bb, acc[1][oj], 0, 0, 0);
        }
    }
    int which = o0 >> 8;          // uniform per block
    int h = (o0 & 255) >> 6;      // uniform per block
    int bh = b * NH + h;
    const float QSC = 0.125f * 1.44269504088896f;
#pragma unroll
    for (int oj = 0; oj < 4; oj++) {
        int o = o0 + oj * 16 + lr;
        float sc = g[o] * rsqrtf(va[o] + 1e-5f);
        float sh = be[o] - mu[o] * sc;
        int d = o & 63;
#pragma unroll
        for (int qi = 0; qi < 2; qi++) {
#pragma unroll
            for (int i = 0; i < 4; i++) {
                float y = acc[qi][oj][i] * sc + sh;
                float z = y / (1.f + __expf(-y));
                int s = s0 + qi * 16 + lg * 4 + i;
                if (which == 0) {
                    Q[((size_t)bh * SLEN + s) * HD + d] = f2bf(z * QSC);
                } else if (which == 1) {
                    Kb[((size_t)bh * SLEN + s) * HD + d] = f2bf(z);
                } else {
                    Vt[((size_t)bh * HD + d) * SLEN + s] = f2bf(z);
                }
            }
        }
    }
}

// ---------------- kernel ATTN: flash attention, pipelined swapped-QK^T ----
// 4 waves/block, 32 q-rows/wave, KVBLK=64. K 2-buf @ lds+0, V 4-buf @ lds+16384.
// Staging via global_load_lds width=16: linear LDS dest + PRE-SWIZZLED per-lane global
// source (reproduces the XOR layout the reads expect). One vmcnt(0)+barrier per tile.
// XCD-aware 1-D block decode: XCD k owns bh {2k,2k+1} (L2 locality).
// S^T = mfma_32x32x16(K, Q): lane holds 32 P values for q = lane&31.
__launch_bounds__(256, 2)
__global__ void k_attn(const short* __restrict__ Q, const short* __restrict__ Kg,
                       const short* __restrict__ Vg, short* __restrict__ aout) {
    __shared__ __align__(16) char lds[16384 + 32768];
    int tid = threadIdx.x;
    int wv = tid >> 6, l = tid & 63;
    int q32 = l & 31;           // q within wave tile (and k-row / d-row for A-frags)
    int hi  = l >> 5;

    // XCD-aware bijective decode (8 XCDs, dispatch round-robin bid%8)
    int bid = blockIdx.x;
    int xcd = bid & 7, slot = bid >> 3;
    int bh = 2 * xcd + (slot & 1);
    int q0 = (slot >> 1) * 128 + wv * 32;

    const short* kg = Kg + (size_t)bh * SLEN * HD;
    const short* vg = Vg + (size_t)bh * HD * SLEN;

    // Q B-fragments: rows q=lane&31, frag jd holds d = jd*16 + hi*8 + 0..7
    bf16x8 qf[4];
    {
        const short* qb = Q + ((size_t)bh * SLEN + q0 + q32) * HD + hi * 8;
        qf[0] = *(const bf16x8*)(qb);
        qf[1] = *(const bf16x8*)(qb + 16);
        qf[2] = *(const bf16x8*)(qb + 32);
        qf[3] = *(const bf16x8*)(qb + 48);
    }

    // ones A-fragment for the row-sum MFMA
    bf16x8 ones;
#pragma unroll
    for (int e = 0; e < 8; ++e) ones[e] = (short)0x3F80;

    f32x16 oacc0 = {}, oacc1 = {}, sacc = {};
    float mrun = 0.0f, bA = 0.0f, bB = 0.0f;

    // ---- async staging geometry ----
    // wave wv stages rows wv*16..wv*16+15 (two gl2lds of 8 rows each, 1KB apiece).
    // gl2lds writes lane l at dest + l*16 (linear); we pre-swizzle the GLOBAL source:
    // lane l covers (row = base + (l>>3), slot = l&7); content col = slot ^ (row&7).
    int colsw = (((l & 7) ^ (l >> 3)) << 4);                  // bytes
    const char* kgB = (const char*)kg;
    const char* vgB = (const char*)vg;
    int ksrc = (wv * 16 + (l >> 3)) * 128 + colsw;            // + t*8192 (+1024 j=1)
    int vsrc = (wv * 16 + (l >> 3)) * 8192 + colsw;           // + t*128  (+65536 j=1)
    int wdst = wv * 2048;                                     // wave-uniform LDS dest

#define STAGE(T, KB, VB) do { \
    gl2lds16(kgB + (size_t)(T) * 8192 + ksrc,          lds + (KB) * 8192 + wdst); \
    gl2lds16(kgB + (size_t)(T) * 8192 + ksrc + 1024,   lds + (KB) * 8192 + wdst + 1024); \
    gl2lds16(vgB + (size_t)(T) * 128 + vsrc,           lds + 16384 + (VB) * 8192 + wdst); \
    gl2lds16(vgB + (size_t)(T) * 128 + vsrc + 65536,   lds + 16384 + (VB) * 8192 + wdst + 1024); \
} while (0)

#define VMBAR() do { \
    asm volatile("s_waitcnt vmcnt(0) lgkmcnt(0)" ::: "memory"); \
    __builtin_amdgcn_s_barrier(); \
    asm volatile("" ::: "memory"); \
} while (0)

    // per-lane read offsets (bytes within a 64x64-short tile); serve K and V
    int swz = (l & 7) << 4;
    int a0 = q32 * 128 + ((0 * 32 + hi * 16) ^ swz);
    int a1 = q32 * 128 + ((1 * 32 + hi * 16) ^ swz);
    int a2 = q32 * 128 + ((2 * 32 + hi * 16) ^ swz);
    int a3 = q32 * 128 + ((3 * 32 + hi * 16) ^ swz);

// QK^T for one tile from K buffer KB, accumulators bias-initialized with -mrun
#define QKT(KB, D0, D1, BSET) do { \
    BSET = mrun; \
    float nb_ = -mrun; \
    _Pragma("unroll") for (int r_ = 0; r_ < 16; ++r_) { D0[r_] = nb_; D1[r_] = nb_; } \
    __builtin_amdgcn_s_setprio(1); \
    { \
        bf16x8 k0_, k1_; \
        k0_ = *(const bf16x8*)(lds + a0 + (KB) * 8192); \
        k1_ = *(const bf16x8*)(lds + a0 + (KB) * 8192 + 4096); \
        D0 = __builtin_amdgcn_mfma_f32_32x32x16_bf16(k0_, qf[0], D0, 0, 0, 0); \
        D1 = __builtin_amdgcn_mfma_f32_32x32x16_bf16(k1_, qf[0], D1, 0, 0, 0); \
        k0_ = *(const bf16x8*)(lds + a1 + (KB) * 8192); \
        k1_ = *(const bf16x8*)(lds + a1 + (KB) * 8192 + 4096); \
        D0 = __builtin_amdgcn_mfma_f32_32x32x16_bf16(k0_, qf[1], D0, 0, 0, 0); \
        D1 = __builtin_amdgcn_mfma_f32_32x32x16_bf16(k1_, qf[1], D1, 0, 0, 0); \
        k0_ = *(const bf16x8*)(lds + a2 + (KB) * 8192); \
        k1_ = *(const bf16x8*)(lds + a2 + (KB) * 8192 + 4096); \
        D0 = __builtin_amdgcn_mfma_f32_32x32x16_bf16(k0_, qf[2], D0, 0, 0, 0); \
        D1 = __builtin_amdgcn_mfma_f32_32x32x16_bf16(k1_, qf[2], D1, 0, 0, 0); \
        k0_ = *(const bf16x8*)(lds + a3 + (KB) * 8192); \
        k1_ = *(const bf16x8*)(lds + a3 + (KB) * 8192 + 4096); \
        D0 = __builtin_amdgcn_mfma_f32_32x32x16_bf16(k0_, qf[3], D0, 0, 0, 0); \
        D1 = __builtin_amdgcn_mfma_f32_32x32x16_bf16(k1_, qf[3], D1, 0, 0, 0); \
    } \
    __builtin_amdgcn_s_setprio(0); \
} while (0)

// one 32-k PV chunk: scores SV[BASE..BASE+7], V cols via addr reg AK, buffer VB
#define PVKC(AK, SV, BASE, VB) do { \
    unsigned A0_ = cvt_pk(SV[(BASE) + 0], SV[(BASE) + 1]); \
    unsigned A1_ = cvt_pk(SV[(BASE) + 2], SV[(BASE) + 3]); \
    unsigned A2_ = cvt_pk(SV[(BASE) + 4], SV[(BASE) + 5]); \
    unsigned A3_ = cvt_pk(SV[(BASE) + 6], SV[(BASE) + 7]); \
    asm volatile("v_permlane32_swap_b32 %0, %1" : "+v"(A0_), "+v"(A2_)); \
    asm volatile("v_permlane32_swap_b32 %0, %1" : "+v"(A1_), "+v"(A3_)); \
    union { bf16x8 v; unsigned u[4]; } pf_; \
    pf_.u[0] = A0_; pf_.u[1] = A1_; pf_.u[2] = A2_; pf_.u[3] = A3_; \
    bf16x8 v0_ = *(const bf16x8*)(lds + (AK) + 16384 + (VB) * 8192); \
    bf16x8 v1_ = *(const bf16x8*)(lds + (AK) + 16384 + (VB) * 8192 + 4096); \
    oacc0 = __builtin_amdgcn_mfma_f32_32x32x16_bf16(v0_, pf_.v, oacc0, 0, 0, 0); \
    oacc1 = __builtin_amdgcn_mfma_f32_32x32x16_bf16(v1_, pf_.v, oacc1, 0, 0, 0); \
    sacc  = __builtin_amdgcn_mfma_f32_32x32x16_bf16(ones, pf_.v, sacc, 0, 0, 0); \
} while (0)

// softmax (biased scores: s = S - BSET) + PV from V buffer VB
#define SMPV(VB, S0, S1, BSET) do { \
    float pa_ = S0[0], pb_ = S0[8], pc_ = S1[0], pd_ = S1[8]; \
    _Pragma("unroll") for (int r_ = 1; r_ < 8; ++r_) { \
        pa_ = fmaxf(pa_, S0[r_]); pb_ = fmaxf(pb_, S0[8 + r_]); \
        pc_ = fmaxf(pc_, S1[r_]); pd_ = fmaxf(pd_, S1[8 + r_]); \
    } \
    float pms_ = fmaxf(fmaxf(pa_, pb_), fmaxf(pc_, pd_)); \
    float c1_ = pms_, c2_ = pms_; \
    asm volatile("" : "+v"(c2_)); /* force distinct register */ \
    asm volatile("v_permlane32_swap_b32 %0, %1" : "+v"(c1_), "+v"(c2_)); \
    pms_ = fmaxf(c1_, c2_); \
    float db_ = mrun - (BSET); \
    if (!__all(pms_ <= db_ + 10.0f)) { \
        float mn_ = fmaxf(mrun, pms_ + (BSET)); \
        float al_ = __builtin_amdgcn_exp2f(mrun - mn_); \
        _Pragma("unroll") for (int r_ = 0; r_ < 16; ++r_) { oacc0[r_] *= al_; oacc1[r_] *= al_; } \
        sacc[0] *= al_; \
        mrun = mn_; db_ = mn_ - (BSET); \
    } \
    if (__all(db_ == 0.0f)) { \
        _Pragma("unroll") for (int r_ = 0; r_ < 16; ++r_) { \
            S0[r_] = __builtin_amdgcn_exp2f(S0[r_]); \
            S1[r_] = __builtin_amdgcn_exp2f(S1[r_]); \
        } \
    } else { \
        _Pragma("unroll") for (int r_ = 0; r_ < 16; ++r_) { \
            S0[r_] = __builtin_amdgcn_exp2f(S0[r_] - db_); \
            S1[r_] = __builtin_amdgcn_exp2f(S1[r_] - db_); \
        } \
    } \
    __builtin_amdgcn_s_setprio(1); \
    PVKC(a0, S0, 0, VB); \
    PVKC(a1, S0, 8, VB); \
    PVKC(a2, S1, 0, VB); \
    PVKC(a3, S1, 8, VB); \
    __builtin_amdgcn_s_setprio(0); \
} while (0)

    f32x16 sA0, sA1, sB0, sB1;

    // prologue: stage 0; drain; stage 1 + QK(0); drain
    STAGE(0, 0, 0);
    VMBAR();
    STAGE(1, 1, 1);
    QKT(0, sA0, sA1, bA);
    VMBAR();

    // steady state: tiles 1..60, unroll 4 (all buffer indices literal)
    for (int j = 0; j < 15; ++j) {
        STAGE(4 * j + 2, 0, 2); QKT(1, sB0, sB1, bB); SMPV(0, sA0, sA1, bA); VMBAR();
        STAGE(4 * j + 3, 1, 3); QKT(0, sA0, sA1, bA); SMPV(1, sB0, sB1, bB); VMBAR();
        STAGE(4 * j + 4, 0, 0); QKT(1, sB0, sB1, bB); SMPV(2, sA0, sA1, bA); VMBAR();
        STAGE(4 * j + 5, 1, 1); QKT(0, sA0, sA1, bA); SMPV(3, sB0, sB1, bB); VMBAR();
    }
    // t = 61
    STAGE(62, 0, 2); QKT(1, sB0, sB1, bB); SMPV(0, sA0, sA1, bA); VMBAR();
    // t = 62
    STAGE(63, 1, 3); QKT(0, sA0, sA1, bA); SMPV(1, sB0, sB1, bB); VMBAR();
    // t = 63
    QKT(1, sB0, sB1, bB); SMPV(2, sA0, sA1, bA);
    // finish tile 63
    SMPV(3, sB0, sB1, bB);

    // ---- epilogue: O^T/l -> aout [b][s][c] bf16 ----
    float inv = 1.f / sacc[0];
    int b = bh >> 2, h = bh & 3;
    short* ob = aout + ((size_t)b * SLEN + q0 + q32) * CIN + h * HD;
#pragma unroll
    for (int g4 = 0; g4 < 4; ++g4) {
        uint2 st0, st1;
        st0.x = cvt_pk(oacc0[4 * g4 + 0] * inv, oacc0[4 * g4 + 1] * inv);
        st0.y = cvt_pk(oacc0[4 * g4 + 2] * inv, oacc0[4 * g4 + 3] * inv);
        st1.x = cvt_pk(oacc1[4 * g4 + 0] * inv, oacc1[4 * g4 + 1] * inv);
        st1.y = cvt_pk(oacc1[4 * g4 + 2] * inv, oacc1[4 * g4 + 3] * inv);
        *(uint2*)(ob + 8 * g4 + 4 * hi) = st0;
        *(uint2*)(ob + 32 + 8 * g4 + 4 * hi) = st1;
    }
#undef STAGE
#undef VMBAR
#undef QKT
#undef PVKC
#undef SMPV
}

// ---------------- kernel C: proj GEMM + BN + SiLU -> fp32 out ----------------
__launch_bounds__(256)
__global__ void k_proj(const short* __restrict__ aout, const short* __restrict__ wbf,
                       const float* __restrict__ g, const float* __restrict__ be,
                       const float* __restrict__ mu, const float* __restrict__ va,
                       float* __restrict__ out) {
    int wv = threadIdx.x >> 6, l = threadIdx.x & 63, lr = l & 15, lg = l >> 4;
    int b = blockIdx.z;
    int s0 = blockIdx.x * 128 + wv * 32;
    int o0 = blockIdx.y * 64;
    f32x4 acc[2][4] = {};
    const short* aptr = aout + ((size_t)b * SLEN + s0 + lr) * CIN + lg * 8;
    const short* bptr = wbf + (size_t)(o0 + lr) * CIN + lg * 8;
#pragma unroll
    for (int k0 = 0; k0 < CIN; k0 += 32) {
        bf16x8 a0 = *(const bf16x8*)(aptr + k0);
        bf16x8 a1 = *(const bf16x8*)(aptr + 16 * CIN + k0);
#pragma unroll
        for (int oj = 0; oj < 4; oj++) {
            bf16x8 bb = *(const bf16x8*)(bptr + oj * 16 * CIN + k0);
            acc[0][oj] = __builtin_amdgcn_mfma_f32_16x16x32_bf16(a0, bb, acc[0][oj], 0, 0, 0);
            acc[1][oj] = __builtin_amdgcn_mfma_f32_16x16x32_bf16(a1, bb, acc[1][oj], 0, 0, 0);
        }
    }
#pragma unroll
    for (int oj = 0; oj < 4; oj++) {
        int o = o0 + oj * 16 + lr;
        float sc = g[o] * rsqrtf(va[o] + 1e-5f);
        float sh = be[o] - mu[o] * sc;
#pragma unroll
        for (int qi = 0; qi < 2; qi++) {
            float4 st;
            float* stp = &st.x;
#pragma unroll
            for (int i = 0; i < 4; i++) {
                float y = acc[qi][oj][i] * sc + sh;
                stp[i] = y / (1.f + __expf(-y));
            }
            int s = s0 + qi * 16 + lg * 4;
            *reinterpret_cast<float4*>(out + ((size_t)b * CIN + o) * SLEN + s) = st;
        }
    }
}

extern "C" void kernel_launch(void* const* d_in, const int* in_sizes, int n_in,
                              void* d_out, int out_size, void* d_ws, size_t ws_size,
                              hipStream_t stream) {
    const float* x    = (const float*)d_in[0];
    const float* qkvw = (const float*)d_in[1];
    const float* qg   = (const float*)d_in[2];
    const float* qbe  = (const float*)d_in[3];
    const float* qmu  = (const float*)d_in[4];
    const float* qva  = (const float*)d_in[5];
    const float* pw   = (const float*)d_in[6];
    const float* pg   = (const float*)d_in[7];
    const float* pbe  = (const float*)d_in[8];
    const float* pmu  = (const float*)d_in[9];
    const float* pva  = (const float*)d_in[10];
    float* out = (float*)d_out;

    char* ws = (char*)d_ws;
    short* xT       = (short*)(ws);                 // 8,388,608 B
    short* qkvw_bf  = (short*)(ws + 8388608);       //   393,216 B
    short* projw_bf = (short*)(ws + 8781824);       //   131,072 B
    short* Qb       = (short*)(ws + 8912896);       // 8,388,608 B
    short* Kb       = (short*)(ws + 17301504);      // 8,388,608 B
    short* Vt       = (short*)(ws + 25690112);      // 8,388,608 B
    short* aout     = (short*)(ws + 34078720);      // 8,388,608 B

    k_convert_w<<<768, 256, 0, stream>>>(qkvw, pw, qkvw_bf, projw_bf);
    k_transpose_x<<<dim3(128, 8, 4), 256, 0, stream>>>(x, xT);
    k_qkv<<<dim3(32, 12, 4), 256, 0, stream>>>(xT, qkvw_bf, qg, qbe, qmu, qva, Qb, Kb, Vt);
    k_attn<<<512, 256, 0, stream>>>(Qb, Kb, Vt, aout);
    k_proj<<<dim3(32, 4, 4), 256, 0, stream>>>(aout, projw_bf, pg, pbe, pmu, pva, out);
}